// Round 1
// baseline (22519.559 us; speedup 1.0000x reference)
//
#include <hip/hip_runtime.h>

#define BB   128   // batch
#define TT   256   // time steps
#define HH   512   // hidden
#define G4   2048  // 4*H
#define OUTN 1024  // output vocab
#define NBLK 256
#define NTHR 512
#define ROWS 16    // batch rows per block
#define NC   16    // hidden cols per block

__device__ __forceinline__ float sigmoidf_(float x) {
    return 1.0f / (1.0f + __expf(-x));
}

__global__ void __launch_bounds__(NTHR, 2)
deeplog_kernel(const int* __restrict__ x,
               const float* __restrict__ Wx1, const float* __restrict__ Wh1, const float* __restrict__ b1,
               const float* __restrict__ Wx2, const float* __restrict__ Wh2, const float* __restrict__ b2,
               const float* __restrict__ Wd,  const float* __restrict__ bd,
               float* __restrict__ out, float* __restrict__ ws)
{
    // LDS: [0 .. ROWS*HH) = h1 rows, [ROWS*HH .. 2*ROWS*HH) = h2 rows  (64 KB exactly)
    __shared__ float lds[2 * ROWS * HH];

    unsigned* bar = (unsigned*)ws;
    unsigned* gen = ((unsigned*)ws) + 1;
    float* Hbase = ws + 64;                       // 256 B offset
    float* H1buf[2] = { Hbase,                Hbase + (size_t)BB * HH };
    float* H2buf[2] = { Hbase + 2ul*BB*HH,    Hbase + 3ul*BB*HH };

    const int bid  = blockIdx.x;
    const int tid  = threadIdx.x;
    const int rb   = bid >> 5;          // 0..7   (row-block)
    const int cb   = bid & 31;          // 0..31  (col-block)
    const int b0   = rb * ROWS;
    const int n0   = cb * NC;
    const int half = tid >> 8;          // 0 = layer1 waves, 1 = layer2 waves
    const int t2   = tid & 255;
    const int r    = t2 >> 4;           // 0..15 local row
    const int nl   = t2 & 15;           // 0..15 local col
    const int n    = n0 + nl;           // hidden index this thread owns
    const int brow = b0 + r;            // batch row this thread owns

    // hoisted biases (gate order i,f,g,o at offsets 0,H,2H,3H)
    float bi, bf, bg, bo;
    if (half == 0) { bi = b1[n]; bf = b1[HH+n]; bg = b1[2*HH+n]; bo = b1[3*HH+n]; }
    else           { bi = b2[n]; bf = b2[HH+n]; bg = b2[2*HH+n]; bo = b2[3*HH+n]; }

    float c_state = 0.0f;   // c1 (half==0) or c2 (half==1) for this (b,n)
    unsigned tgt = 1;

    #pragma unroll 1
    for (int p = 0; p <= TT; ++p) {
        // ---- stage h1_{p-1}, h2_{p-2} rows b0..b0+15 into LDS (contiguous copy) ----
        {
            const float4* s1 = (const float4*)(H1buf[p & 1] + (size_t)b0 * HH);
            const float4* s2 = (const float4*)(H2buf[p & 1] + (size_t)b0 * HH);
            float4* d1 = (float4*)lds;
            float4* d2 = (float4*)(lds + ROWS * HH);
            #pragma unroll
            for (int i = 0; i < (ROWS * HH / 4) / NTHR; ++i) {   // 4 iters
                d1[tid + i * NTHR] = s1[tid + i * NTHR];
                d2[tid + i * NTHR] = s2[tid + i * NTHR];
            }
        }
        __syncthreads();

        if (half == 0) {
            if (p < TT) {
                // layer 1, step p: z = Wx1[x_p] + h1_prev @ Wh1 + b1
                const int xrow = x[brow * TT + p];
                const float* wx = Wx1 + (size_t)xrow * G4 + n;
                float a0 = bi + wx[0];
                float a1 = bf + wx[HH];
                float a2 = bg + wx[2*HH];
                float a3 = bo + wx[3*HH];
                const float4* hp  = (const float4*)(lds + r * HH);
                const float* wcol = Wh1 + n;
                #pragma unroll 2
                for (int k4 = 0; k4 < HH/4; ++k4) {
                    float4 h4 = hp[k4];
                    const float* w = wcol + (size_t)k4 * 4 * G4;
                    a0 += h4.x*w[0];      a1 += h4.x*w[HH];       a2 += h4.x*w[2*HH];       a3 += h4.x*w[3*HH];
                    a0 += h4.y*w[G4];     a1 += h4.y*w[G4+HH];    a2 += h4.y*w[G4+2*HH];    a3 += h4.y*w[G4+3*HH];
                    a0 += h4.z*w[2*G4];   a1 += h4.z*w[2*G4+HH];  a2 += h4.z*w[2*G4+2*HH];  a3 += h4.z*w[2*G4+3*HH];
                    a0 += h4.w*w[3*G4];   a1 += h4.w*w[3*G4+HH];  a2 += h4.w*w[3*G4+2*HH];  a3 += h4.w*w[3*G4+3*HH];
                }
                float gi = sigmoidf_(a0);
                float gf = sigmoidf_(a1);
                float gg = tanhf(a2);
                float go = sigmoidf_(a3);
                c_state  = gf * c_state + gi * gg;
                float hn = go * tanhf(c_state);
                H1buf[(p + 1) & 1][(size_t)brow * HH + n] = hn;
            }
        } else {
            if (p >= 1) {
                // layer 2, step p-1: z = h1_{p-1} @ Wx2 + h2_{p-2} @ Wh2 + b2
                float a0 = bi, a1 = bf, a2 = bg, a3 = bo;
                const float4* h1p = (const float4*)(lds + r * HH);
                const float4* h2p = (const float4*)(lds + ROWS * HH + r * HH);
                const float* wa = Wx2 + n;
                const float* wb = Wh2 + n;
                #pragma unroll 1
                for (int k4 = 0; k4 < HH/4; ++k4) {
                    float4 u = h1p[k4];
                    float4 v = h2p[k4];
                    const float* wA = wa + (size_t)k4 * 4 * G4;
                    const float* wB = wb + (size_t)k4 * 4 * G4;
                    a0 += u.x*wA[0]        + v.x*wB[0];
                    a1 += u.x*wA[HH]       + v.x*wB[HH];
                    a2 += u.x*wA[2*HH]     + v.x*wB[2*HH];
                    a3 += u.x*wA[3*HH]     + v.x*wB[3*HH];
                    a0 += u.y*wA[G4]       + v.y*wB[G4];
                    a1 += u.y*wA[G4+HH]    + v.y*wB[G4+HH];
                    a2 += u.y*wA[G4+2*HH]  + v.y*wB[G4+2*HH];
                    a3 += u.y*wA[G4+3*HH]  + v.y*wB[G4+3*HH];
                    a0 += u.z*wA[2*G4]     + v.z*wB[2*G4];
                    a1 += u.z*wA[2*G4+HH]  + v.z*wB[2*G4+HH];
                    a2 += u.z*wA[2*G4+2*HH]+ v.z*wB[2*G4+2*HH];
                    a3 += u.z*wA[2*G4+3*HH]+ v.z*wB[2*G4+3*HH];
                    a0 += u.w*wA[3*G4]     + v.w*wB[3*G4];
                    a1 += u.w*wA[3*G4+HH]  + v.w*wB[3*G4+HH];
                    a2 += u.w*wA[3*G4+2*HH]+ v.w*wB[3*G4+2*HH];
                    a3 += u.w*wA[3*G4+3*HH]+ v.w*wB[3*G4+3*HH];
                }
                float gi = sigmoidf_(a0);
                float gf = sigmoidf_(a1);
                float gg = tanhf(a2);
                float go = sigmoidf_(a3);
                c_state  = gf * c_state + gi * gg;
                float hn = go * tanhf(c_state);
                H2buf[(p + 1) & 1][(size_t)brow * HH + n] = hn;
            }
        }

        // ---- grid barrier (agent-scope) ----
        __syncthreads();
        if (tid == 0) {
            __threadfence();  // publish this block's h stores at agent scope
            unsigned prev = __hip_atomic_fetch_add(bar, 1u, __ATOMIC_ACQ_REL, __HIP_MEMORY_SCOPE_AGENT);
            if (prev == NBLK - 1) {
                __hip_atomic_store(bar, 0u, __ATOMIC_RELAXED, __HIP_MEMORY_SCOPE_AGENT);
                __hip_atomic_store(gen, tgt, __ATOMIC_RELEASE, __HIP_MEMORY_SCOPE_AGENT);
            } else {
                while (__hip_atomic_load(gen, __ATOMIC_ACQUIRE, __HIP_MEMORY_SCOPE_AGENT) < tgt) {
                    __builtin_amdgcn_s_sleep(1);
                }
            }
        }
        ++tgt;
        __syncthreads();
    }

    // ---- final dense + softmax: block b handles output row b ----
    if (bid < BB) {
        const float* h2f = H2buf[(TT + 1) & 1] + (size_t)bid * HH;
        float* hrow = lds;            // 512 floats
        float* red  = lds + HH;       // 512 floats
        if (tid < HH) hrow[tid] = h2f[tid];
        __syncthreads();

        float a0 = bd[tid], a1 = bd[tid + 512];
        const float* w = Wd + tid;
        #pragma unroll 4
        for (int k = 0; k < HH; ++k) {
            float hv = hrow[k];
            a0 += hv * w[(size_t)k * OUTN];
            a1 += hv * w[(size_t)k * OUTN + 512];
        }

        red[tid] = fmaxf(a0, a1);
        __syncthreads();
        for (int s = NTHR / 2; s > 0; s >>= 1) {
            if (tid < s) red[tid] = fmaxf(red[tid], red[tid + s]);
            __syncthreads();
        }
        float M = red[0];
        __syncthreads();
        float e0 = __expf(a0 - M), e1 = __expf(a1 - M);
        red[tid] = e0 + e1;
        __syncthreads();
        for (int s = NTHR / 2; s > 0; s >>= 1) {
            if (tid < s) red[tid] += red[tid + s];
            __syncthreads();
        }
        float inv = 1.0f / red[0];
        out[(size_t)bid * OUTN + tid]       = e0 * inv;
        out[(size_t)bid * OUTN + tid + 512] = e1 * inv;
    }
}

extern "C" void kernel_launch(void* const* d_in, const int* in_sizes, int n_in,
                              void* d_out, int out_size, void* d_ws, size_t ws_size,
                              hipStream_t stream) {
    (void)in_sizes; (void)n_in; (void)out_size; (void)ws_size;

    const int*   x   = (const int*)  d_in[0];
    const float* Wx1 = (const float*)d_in[1];
    const float* Wh1 = (const float*)d_in[2];
    const float* b1  = (const float*)d_in[3];
    const float* Wx2 = (const float*)d_in[4];
    const float* Wh2 = (const float*)d_in[5];
    const float* b2  = (const float*)d_in[6];
    const float* Wd  = (const float*)d_in[7];
    const float* bd  = (const float*)d_in[8];
    float* out = (float*)d_out;
    float* ws  = (float*)d_ws;

    // zero barrier counters + all four h state buffers (ws is poisoned 0xAA each call)
    size_t zero_bytes = 256 + (size_t)4 * BB * HH * sizeof(float);
    hipMemsetAsync(d_ws, 0, zero_bytes, stream);

    void* args[] = { &x, &Wx1, &Wh1, &b1, &Wx2, &Wh2, &b2, &Wd, &bd, &out, &ws };
    hipLaunchCooperativeKernel((const void*)deeplog_kernel,
                               dim3(NBLK), dim3(NTHR), args, 0, stream);
}

// Round 3
// 11976.704 us; speedup vs baseline: 1.8803x; 1.8803x over previous
//
#include <hip/hip_runtime.h>

#define BB   128   // batch
#define TT   256   // time steps
#define HH   512   // hidden
#define G4   2048  // 4*H
#define OUTN 1024  // output vocab
#define NBLK 256
#define NTHR 512

// LDS geometry
#define WSTRIDE 520                 // padded col-major stride (elems) -> 2-way banks only
#define WREG    (16 * WSTRIDE)      // one weight region: 16 gate-cols x 520
#define ZOFF    (6 * WREG * 2)      // byte offset of z scratch (6 regions of bf16) = 99840
#define ZSTRIDE 20                  // padded z row stride (floats)
#define LDS_BYTES (ZOFF + 2 * 64 * ZSTRIDE * 4)   // 99840 + 10240 = 110080

typedef __attribute__((ext_vector_type(8))) short  v8s;   // 8 bf16 (4 VGPRs)
typedef __attribute__((ext_vector_type(4))) float  v4f;   // MFMA acc

__device__ __forceinline__ float sigmoidf_(float x) {
    return 1.0f / (1.0f + __expf(-x));
}
__device__ __forceinline__ unsigned short f2bf_rn(float f) {
    unsigned u = __float_as_uint(f);
    unsigned r = u + 0x7fffu + ((u >> 16) & 1u);
    return (unsigned short)(r >> 16);
}
__device__ __forceinline__ float bf2f(unsigned short h) {
    return __uint_as_float(((unsigned)h) << 16);
}

// 16 K-iters (K=512) of split-bf16 MFMA: acc += A*B with A=Ah+Al, B=Bh+Bl (all 4 products)
__device__ __forceinline__ void gemm16(v4f& accP, v4f& accQ,
    const unsigned short* __restrict__ Ah, const unsigned short* __restrict__ Al,
    const unsigned short* __restrict__ Bh, const unsigned short* __restrict__ Bl)
{
    #pragma unroll
    for (int kk = 0; kk < 16; ++kk) {
        v8s ah = *(const v8s*)(Ah + kk * 32);
        v8s al = *(const v8s*)(Al + kk * 32);
        v8s bh = *(const v8s*)(Bh + kk * 32);
        v8s bl = *(const v8s*)(Bl + kk * 32);
        accP = __builtin_amdgcn_mfma_f32_16x16x32_bf16(ah, bh, accP, 0, 0, 0);
        accP = __builtin_amdgcn_mfma_f32_16x16x32_bf16(al, bl, accP, 0, 0, 0);
        accQ = __builtin_amdgcn_mfma_f32_16x16x32_bf16(ah, bl, accQ, 0, 0, 0);
        accQ = __builtin_amdgcn_mfma_f32_16x16x32_bf16(al, bh, accQ, 0, 0, 0);
    }
}

__global__ void __launch_bounds__(NTHR, 1)
deeplog_kernel(const int* __restrict__ x,
               const float* __restrict__ Wx1, const float* __restrict__ Wh1, const float* __restrict__ b1,
               const float* __restrict__ Wx2, const float* __restrict__ Wh2, const float* __restrict__ b2,
               const float* __restrict__ Wd,  const float* __restrict__ bd,
               float* __restrict__ out, void* __restrict__ wsv)
{
    extern __shared__ char smem[];
    unsigned short* wlds = (unsigned short*)smem;            // 6 x [16][520] bf16 weight regions
    float* zlds = (float*)(smem + ZOFF);                     // [2][64][20] f32 preactivations

    char* wsb = (char*)wsv;
    unsigned* bar = (unsigned*)wsb;
    unsigned* gen = ((unsigned*)wsb) + 1;
    unsigned short* Hbase = (unsigned short*)(wsb + 256);
    // H state buffers, each [128][512] bf16 (65536 elems): parity double-buffered hi/lo
    unsigned short* H1hi[2] = { Hbase,           Hbase + 65536 };
    unsigned short* H1lo[2] = { Hbase + 131072,  Hbase + 196608 };
    unsigned short* H2hi[2] = { Hbase + 262144,  Hbase + 327680 };
    unsigned short* H2lo[2] = { Hbase + 393216,  Hbase + 458752 };

    const int bid  = blockIdx.x;
    const int tid  = threadIdx.x;
    const int rb   = bid >> 7;           // 0..1 row-group
    const int cb   = bid & 127;          // 0..127 col-group
    const int b0   = rb * 64;            // first batch row of block
    const int n0   = cb * 4;             // first hidden unit of block

    const int lane = tid & 63;
    const int wv   = tid >> 6;           // wave 0..7
    const int isL2 = (wv >= 4);          // waves 4-7 -> layer 2
    const int wt   = isL2 ? (wv - 4) : wv;       // row-tile within block (16 rows each)
    const int kgrp = (lane >> 4) * 8;            // k-slot group for A/B fragments
    const int colb = (lane & 15) * WSTRIDE + kgrp;
    const int aoff = ((b0 + wt * 16 + (lane & 15)) << 9) + kgrp;  // row*512 + kgrp

    // gate-stage ownership: thread t -> layer (t>>8), cell (row=(t&255)>>2, nl=t&3)
    const int Lme  = tid >> 8;           // == isL2
    const int u    = tid & 255;
    const int grow = u >> 2;             // 0..63 local row
    const int nl   = u & 3;
    const int rowg = b0 + grow;          // global batch row
    const int n    = n0 + nl;            // global hidden unit

    // ---- one-time: stage split-bf16 weights to LDS (col-major, padded) ----
    for (int m = 0; m < 3; ++m) {
        const float* Wsrc = (m == 0) ? Wh1 : (m == 1) ? Wx2 : Wh2;
        unsigned short* dhi = wlds + (2 * m) * WREG;
        unsigned short* dlo = wlds + (2 * m + 1) * WREG;
        for (int i = tid; i < 8192; i += NTHR) {
            int k = i >> 4, c = i & 15;
            float v = Wsrc[(size_t)k * G4 + ((c >> 2) << 9) + n0 + (c & 3)];
            unsigned short hi = f2bf_rn(v);
            unsigned short lo = f2bf_rn(v - bf2f(hi));
            dhi[c * WSTRIDE + k] = hi;
            dlo[c * WSTRIDE + k] = lo;
        }
    }
    __syncthreads();

    const unsigned short* wh1h = wlds;
    const unsigned short* wh1l = wlds + WREG;
    const unsigned short* wx2h = wlds + 2 * WREG;
    const unsigned short* wx2l = wlds + 3 * WREG;
    const unsigned short* wh2h = wlds + 4 * WREG;
    const unsigned short* wh2l = wlds + 5 * WREG;

    // hoisted biases for owned cell (gate order i,f,g,o)
    const float* bsrc = Lme ? b2 : b1;
    float bias0 = bsrc[n], bias1 = bsrc[HH + n], bias2 = bsrc[2 * HH + n], bias3 = bsrc[3 * HH + n];

    float c_state = 0.0f;
    unsigned tgt = 1;

    #pragma unroll 1
    for (int p = 0; p <= TT; ++p) {
        // prefetch one-hot row of Wx1 for the gate stage (independent of barrier)
        float wx0 = 0.f, wx1v = 0.f, wx2v = 0.f, wx3v = 0.f;
        if (Lme == 0 && p < TT) {
            int xr = x[rowg * TT + p];
            const float* wxp = Wx1 + (size_t)xr * G4 + n;
            wx0 = wxp[0]; wx1v = wxp[HH]; wx2v = wxp[2 * HH]; wx3v = wxp[3 * HH];
        }

        // ---- MFMA GEMMs ----
        const int q1 = (p - 1) & 1;   // parity holding h1(p-1)
        const int q2 = p & 1;         // parity holding h2(p-2)
        if (!isL2) {
            if (p < TT) {
                v4f accP = {0.f, 0.f, 0.f, 0.f}, accQ = {0.f, 0.f, 0.f, 0.f};
                gemm16(accP, accQ, H1hi[q1] + aoff, H1lo[q1] + aoff, wh1h + colb, wh1l + colb);
                int r0 = wt * 16 + ((lane >> 4) << 2);
                #pragma unroll
                for (int q = 0; q < 4; ++q)
                    zlds[(r0 + q) * ZSTRIDE + (lane & 15)] = accP[q] + accQ[q];
            }
        } else {
            if (p >= 1) {
                v4f accP = {0.f, 0.f, 0.f, 0.f}, accQ = {0.f, 0.f, 0.f, 0.f};
                gemm16(accP, accQ, H1hi[q1] + aoff, H1lo[q1] + aoff, wx2h + colb, wx2l + colb);
                gemm16(accP, accQ, H2hi[q2] + aoff, H2lo[q2] + aoff, wh2h + colb, wh2l + colb);
                int r0 = wt * 16 + ((lane >> 4) << 2);
                #pragma unroll
                for (int q = 0; q < 4; ++q)
                    zlds[64 * ZSTRIDE + (r0 + q) * ZSTRIDE + (lane & 15)] = accP[q] + accQ[q];
            }
        }
        __syncthreads();

        // ---- gates: thread owns one (layer, row, n) cell; c-state in register ----
        bool act = (Lme == 0) ? (p < TT) : (p >= 1);
        if (act) {
            const float* zrow = zlds + Lme * (64 * ZSTRIDE) + grow * ZSTRIDE;
            float z0 = zrow[nl]      + bias0;
            float z1 = zrow[4 + nl]  + bias1;
            float z2 = zrow[8 + nl]  + bias2;
            float z3 = zrow[12 + nl] + bias3;
            if (Lme == 0) { z0 += wx0; z1 += wx1v; z2 += wx2v; z3 += wx3v; }
            float gi = sigmoidf_(z0);
            float gf = sigmoidf_(z1);
            float gg = tanhf(z2);
            float go = sigmoidf_(z3);
            c_state  = gf * c_state + gi * gg;
            float h  = go * tanhf(c_state);
            unsigned short hhi = f2bf_rn(h);
            unsigned short hlo = f2bf_rn(h - bf2f(hhi));
            size_t hoff = (size_t)rowg * HH + n;
            if (Lme == 0) { H1hi[p & 1][hoff] = hhi;       H1lo[p & 1][hoff] = hlo; }
            else          { H2hi[(p - 1) & 1][hoff] = hhi; H2lo[(p - 1) & 1][hoff] = hlo; }
        }

        // ---- grid barrier (agent-scope); each wave drains own vmcnt at syncthreads,
        // leader's threadfence publishes the XCD L2 ----
        __syncthreads();
        if (tid == 0) {
            __threadfence();
            unsigned prev = __hip_atomic_fetch_add(bar, 1u, __ATOMIC_ACQ_REL, __HIP_MEMORY_SCOPE_AGENT);
            if (prev == NBLK - 1) {
                __hip_atomic_store(bar, 0u, __ATOMIC_RELAXED, __HIP_MEMORY_SCOPE_AGENT);
                __hip_atomic_store(gen, tgt, __ATOMIC_RELEASE, __HIP_MEMORY_SCOPE_AGENT);
            } else {
                while (__hip_atomic_load(gen, __ATOMIC_ACQUIRE, __HIP_MEMORY_SCOPE_AGENT) < tgt) {
                    __builtin_amdgcn_s_sleep(1);
                }
            }
        }
        ++tgt;
        __syncthreads();
    }

    // ---- final dense + softmax: block b handles output row b ----
    if (bid < BB) {
        const unsigned short* h2hi = H2hi[(TT - 1) & 1] + (size_t)bid * HH;
        const unsigned short* h2lo = H2lo[(TT - 1) & 1] + (size_t)bid * HH;
        float* hrow = zlds;            // 512 floats
        float* red  = zlds + HH;       // 512 floats
        hrow[tid] = bf2f(h2hi[tid]) + bf2f(h2lo[tid]);
        __syncthreads();

        float a0 = bd[tid], a1 = bd[tid + 512];
        const float* w = Wd + tid;
        #pragma unroll 4
        for (int k = 0; k < HH; ++k) {
            float hv = hrow[k];
            a0 += hv * w[(size_t)k * OUTN];
            a1 += hv * w[(size_t)k * OUTN + 512];
        }

        red[tid] = fmaxf(a0, a1);
        __syncthreads();
        for (int s = NTHR / 2; s > 0; s >>= 1) {
            if (tid < s) red[tid] = fmaxf(red[tid], red[tid + s]);
            __syncthreads();
        }
        float M = red[0];
        __syncthreads();
        float e0 = __expf(a0 - M), e1 = __expf(a1 - M);
        red[tid] = e0 + e1;
        __syncthreads();
        for (int s = NTHR / 2; s > 0; s >>= 1) {
            if (tid < s) red[tid] += red[tid + s];
            __syncthreads();
        }
        float inv = 1.0f / red[0];
        out[(size_t)bid * OUTN + tid]       = e0 * inv;
        out[(size_t)bid * OUTN + tid + 512] = e1 * inv;
    }
}

extern "C" void kernel_launch(void* const* d_in, const int* in_sizes, int n_in,
                              void* d_out, int out_size, void* d_ws, size_t ws_size,
                              hipStream_t stream) {
    (void)in_sizes; (void)n_in; (void)out_size; (void)ws_size;

    const int*   x   = (const int*)  d_in[0];
    const float* Wx1 = (const float*)d_in[1];
    const float* Wh1 = (const float*)d_in[2];
    const float* b1  = (const float*)d_in[3];
    const float* Wx2 = (const float*)d_in[4];
    const float* Wh2 = (const float*)d_in[5];
    const float* b2  = (const float*)d_in[6];
    const float* Wd  = (const float*)d_in[7];
    const float* bd  = (const float*)d_in[8];
    float* out = (float*)d_out;
    void* ws   = d_ws;

    // allow >64KB dynamic LDS (110080 B); harmless if already permitted
    (void)hipFuncSetAttribute((const void*)deeplog_kernel,
                              hipFuncAttributeMaxDynamicSharedMemorySize, LDS_BYTES);

    // zero barrier counters + all h-state bf16 buffers (ws poisoned 0xAA each call)
    size_t zero_bytes = 256 + (size_t)8 * BB * HH * sizeof(unsigned short);  // 1,048,832
    hipMemsetAsync(d_ws, 0, zero_bytes, stream);

    void* args[] = { &x, &Wx1, &Wh1, &b1, &Wx2, &Wh2, &b2, &Wd, &bd, &out, &ws };
    hipLaunchCooperativeKernel((const void*)deeplog_kernel,
                               dim3(NBLK), dim3(NTHR), args, LDS_BYTES, stream);
}

// Round 4
// 7190.744 us; speedup vs baseline: 3.1317x; 1.6656x over previous
//
#include <hip/hip_runtime.h>

#define BB   128   // batch
#define TT   256   // time steps
#define HH   512   // hidden
#define G4   2048  // 4*H
#define OUTN 1024  // output vocab
#define NBLK 256
#define NTHR 512

// LDS geometry
#define WSTRIDE 520                 // padded col-major stride (elems)
#define WREG    (16 * WSTRIDE)      // one weight region: 16 gate-cols x 520
#define ZOFF    (6 * WREG * 2)      // byte offset of z scratch = 99840
#define ZSTRIDE 20                  // padded z row stride (floats)
#define LDS_BYTES (ZOFF + 2 * 64 * ZSTRIDE * 4)   // 110080

// workspace layout (bytes): [4096,20480) flags (u32 every 64B), [32768,..) H buffers
#define FLAG_OFF  4096
#define FLAG_STRIDE 16              // u32 elements -> 64 B apart
#define H_OFF     32768

typedef __attribute__((ext_vector_type(8))) short  v8s;   // 8 bf16 (4 VGPRs)
typedef __attribute__((ext_vector_type(4))) float  v4f;   // MFMA acc

__device__ __forceinline__ float sigmoidf_(float x) {
    return 1.0f / (1.0f + __expf(-x));
}
__device__ __forceinline__ unsigned short f2bf_rn(float f) {
    unsigned u = __float_as_uint(f);
    unsigned r = u + 0x7fffu + ((u >> 16) & 1u);
    return (unsigned short)(r >> 16);
}
__device__ __forceinline__ float bf2f(unsigned short h) {
    return __uint_as_float(((unsigned)h) << 16);
}

// Split-bf16 GEMM over K=512: prefetch ALL A fragments (hi+lo) into registers
// (static indices -> VGPRs, one L3 round-trip for 32 parallel loads), then MFMA.
// Order P,Q,P,Q so dependent same-acc MFMAs are 2 apart (acc-chain stall halved).
__device__ __forceinline__ void gemm16_pre(v4f& accP, v4f& accQ,
    const unsigned short* __restrict__ Ah, const unsigned short* __restrict__ Al,
    const unsigned short* __restrict__ Bh, const unsigned short* __restrict__ Bl)
{
    v8s ah[16], al[16];
    #pragma unroll
    for (int kk = 0; kk < 16; ++kk) {
        ah[kk] = *(const v8s*)(Ah + kk * 32);
        al[kk] = *(const v8s*)(Al + kk * 32);
    }
    #pragma unroll
    for (int kk = 0; kk < 16; ++kk) {
        v8s bh = *(const v8s*)(Bh + kk * 32);
        v8s bl = *(const v8s*)(Bl + kk * 32);
        accP = __builtin_amdgcn_mfma_f32_16x16x32_bf16(ah[kk], bh, accP, 0, 0, 0);
        accQ = __builtin_amdgcn_mfma_f32_16x16x32_bf16(ah[kk], bl, accQ, 0, 0, 0);
        accP = __builtin_amdgcn_mfma_f32_16x16x32_bf16(al[kk], bl, accP, 0, 0, 0);
        accQ = __builtin_amdgcn_mfma_f32_16x16x32_bf16(al[kk], bh, accQ, 0, 0, 0);
    }
}

__global__ void __launch_bounds__(NTHR, 1)
deeplog_kernel(const int* __restrict__ x,
               const float* __restrict__ Wx1, const float* __restrict__ Wh1, const float* __restrict__ b1,
               const float* __restrict__ Wx2, const float* __restrict__ Wh2, const float* __restrict__ b2,
               const float* __restrict__ Wd,  const float* __restrict__ bd,
               float* __restrict__ out, void* __restrict__ wsv)
{
    extern __shared__ char smem[];
    unsigned short* wlds = (unsigned short*)smem;            // 6 x [16][520] bf16 weight regions
    float* zlds = (float*)(smem + ZOFF);                     // [2][64][20] f32 preactivations

    char* wsb = (char*)wsv;
    unsigned* flags = (unsigned*)(wsb + FLAG_OFF);           // flag[i] at flags[i*FLAG_STRIDE]
    unsigned short* Hbase = (unsigned short*)(wsb + H_OFF);
    unsigned short* H1hi[2] = { Hbase,           Hbase + 65536 };
    unsigned short* H1lo[2] = { Hbase + 131072,  Hbase + 196608 };
    unsigned short* H2hi[2] = { Hbase + 262144,  Hbase + 327680 };
    unsigned short* H2lo[2] = { Hbase + 393216,  Hbase + 458752 };

    const int bid  = blockIdx.x;
    const int tid  = threadIdx.x;
    const int rb   = bid >> 7;           // 0..1 row-group
    const int cb   = bid & 127;          // 0..127 col-group
    const int b0   = rb * 64;            // first batch row of block
    const int n0   = cb * 4;             // first hidden unit of block

    const int lane = tid & 63;
    const int wv   = tid >> 6;           // wave 0..7
    const int isL2 = (wv >= 4);          // waves 4-7 -> layer 2
    const int wt   = isL2 ? (wv - 4) : wv;       // row-tile within block (16 rows each)
    const int kgrp = (lane >> 4) * 8;            // k-slot group for A/B fragments
    const int colb = (lane & 15) * WSTRIDE + kgrp;
    const int aoff = ((b0 + wt * 16 + (lane & 15)) << 9) + kgrp;  // row*512 + kgrp

    // gate-stage ownership: thread t -> layer (t>>8), cell (row=(t&255)>>2, nl=t&3)
    const int Lme  = tid >> 8;           // == isL2
    const int u    = tid & 255;
    const int grow = u >> 2;             // 0..63 local row
    const int nl   = u & 3;
    const int rowg = b0 + grow;          // global batch row
    const int n    = n0 + nl;            // global hidden unit

    // ---- one-time: stage split-bf16 weights to LDS (col-major, padded) ----
    for (int m = 0; m < 3; ++m) {
        const float* Wsrc = (m == 0) ? Wh1 : (m == 1) ? Wx2 : Wh2;
        unsigned short* dhi = wlds + (2 * m) * WREG;
        unsigned short* dlo = wlds + (2 * m + 1) * WREG;
        for (int i = tid; i < 8192; i += NTHR) {
            int k = i >> 4, c = i & 15;
            float v = Wsrc[(size_t)k * G4 + ((c >> 2) << 9) + n0 + (c & 3)];
            unsigned short hi = f2bf_rn(v);
            unsigned short lo = f2bf_rn(v - bf2f(hi));
            dhi[c * WSTRIDE + k] = hi;
            dlo[c * WSTRIDE + k] = lo;
        }
    }
    __syncthreads();

    const unsigned short* wh1h = wlds;
    const unsigned short* wh1l = wlds + WREG;
    const unsigned short* wx2h = wlds + 2 * WREG;
    const unsigned short* wx2l = wlds + 3 * WREG;
    const unsigned short* wh2h = wlds + 4 * WREG;
    const unsigned short* wh2l = wlds + 5 * WREG;

    // hoisted biases for owned cell (gate order i,f,g,o)
    const float* bsrc = Lme ? b2 : b1;
    float bias0 = bsrc[n], bias1 = bsrc[HH + n], bias2 = bsrc[2 * HH + n], bias3 = bsrc[3 * HH + n];

    float c_state = 0.0f;
    unsigned tgt = 1;

    #pragma unroll 1
    for (int p = 0; p <= TT; ++p) {
        // prefetch one-hot row of Wx1 for the gate stage (long slack before use)
        float wx0 = 0.f, wx1v = 0.f, wx2v = 0.f, wx3v = 0.f;
        if (Lme == 0 && p < TT) {
            int xr = x[rowg * TT + p];
            const float* wxp = Wx1 + (size_t)xr * G4 + n;
            wx0 = wxp[0]; wx1v = wxp[HH]; wx2v = wxp[2 * HH]; wx3v = wxp[3 * HH];
        }

        // ---- MFMA GEMMs ----
        const int q1 = (p - 1) & 1;   // parity holding h1(p-1)
        const int q2 = p & 1;         // parity holding h2(p-2)
        if (!isL2) {
            if (p < TT) {
                v4f accP = {0.f, 0.f, 0.f, 0.f}, accQ = {0.f, 0.f, 0.f, 0.f};
                gemm16_pre(accP, accQ, H1hi[q1] + aoff, H1lo[q1] + aoff, wh1h + colb, wh1l + colb);
                int r0 = wt * 16 + ((lane >> 4) << 2);
                #pragma unroll
                for (int q = 0; q < 4; ++q)
                    zlds[(r0 + q) * ZSTRIDE + (lane & 15)] = accP[q] + accQ[q];
            }
        } else {
            if (p >= 1) {
                v4f accP = {0.f, 0.f, 0.f, 0.f}, accQ = {0.f, 0.f, 0.f, 0.f};
                gemm16_pre(accP, accQ, H1hi[q1] + aoff, H1lo[q1] + aoff, wx2h + colb, wx2l + colb);
                gemm16_pre(accP, accQ, H2hi[q2] + aoff, H2lo[q2] + aoff, wh2h + colb, wh2l + colb);
                int r0 = wt * 16 + ((lane >> 4) << 2);
                #pragma unroll
                for (int q = 0; q < 4; ++q)
                    zlds[64 * ZSTRIDE + (r0 + q) * ZSTRIDE + (lane & 15)] = accP[q] + accQ[q];
            }
        }
        __syncthreads();

        // ---- gates: thread owns one (layer, row, n) cell; c-state in register ----
        bool act = (Lme == 0) ? (p < TT) : (p >= 1);
        if (act) {
            const float* zrow = zlds + Lme * (64 * ZSTRIDE) + grow * ZSTRIDE;
            float z0 = zrow[nl]      + bias0;
            float z1 = zrow[4 + nl]  + bias1;
            float z2 = zrow[8 + nl]  + bias2;
            float z3 = zrow[12 + nl] + bias3;
            if (Lme == 0) { z0 += wx0; z1 += wx1v; z2 += wx2v; z3 += wx3v; }
            float gi = sigmoidf_(z0);
            float gf = sigmoidf_(z1);
            float gg = tanhf(z2);
            float go = sigmoidf_(z3);
            c_state  = gf * c_state + gi * gg;
            float h  = go * tanhf(c_state);
            unsigned short hhi = f2bf_rn(h);
            unsigned short hlo = f2bf_rn(h - bf2f(hhi));
            size_t hoff = (size_t)rowg * HH + n;
            if (Lme == 0) { H1hi[p & 1][hoff] = hhi;       H1lo[p & 1][hoff] = hlo; }
            else          { H2hi[(p - 1) & 1][hoff] = hhi; H2lo[(p - 1) & 1][hoff] = hlo; }
        }

        // ---- flag-array grid barrier: parallel arrival, distributed detection ----
        // arrival: release-store own flag (agent release = wbL2 flush of our h stores,
        // syncthreads above already drained each thread's vmcnt into local L2)
        __syncthreads();
        if (tid == 0)
            __hip_atomic_store(&flags[bid * FLAG_STRIDE], tgt,
                               __ATOMIC_RELEASE, __HIP_MEMORY_SCOPE_AGENT);
        // detection: thread t<256 waits for block t's flag; RELAXED polls (no inv per poll)
        if (tid < NBLK) {
            while (__hip_atomic_load(&flags[tid * FLAG_STRIDE],
                                     __ATOMIC_RELAXED, __HIP_MEMORY_SCOPE_AGENT) < tgt)
                __builtin_amdgcn_s_sleep(1);
        }
        __syncthreads();
        // one acquire per block: invalidate L1/L2 so next phase's h reads see remote data
        if (tid == 0)
            (void)__hip_atomic_load(&flags[bid * FLAG_STRIDE],
                                    __ATOMIC_ACQUIRE, __HIP_MEMORY_SCOPE_AGENT);
        ++tgt;
        __syncthreads();
    }

    // ---- final dense + softmax: block b handles output row b ----
    if (bid < BB) {
        const unsigned short* h2hi = H2hi[(TT - 1) & 1] + (size_t)bid * HH;
        const unsigned short* h2lo = H2lo[(TT - 1) & 1] + (size_t)bid * HH;
        float* hrow = zlds;            // 512 floats
        float* red  = zlds + HH;       // 512 floats
        hrow[tid] = bf2f(h2hi[tid]) + bf2f(h2lo[tid]);
        __syncthreads();

        float a0 = bd[tid], a1 = bd[tid + 512];
        const float* w = Wd + tid;
        #pragma unroll 4
        for (int k = 0; k < HH; ++k) {
            float hv = hrow[k];
            a0 += hv * w[(size_t)k * OUTN];
            a1 += hv * w[(size_t)k * OUTN + 512];
        }

        red[tid] = fmaxf(a0, a1);
        __syncthreads();
        for (int s = NTHR / 2; s > 0; s >>= 1) {
            if (tid < s) red[tid] = fmaxf(red[tid], red[tid + s]);
            __syncthreads();
        }
        float M = red[0];
        __syncthreads();
        float e0 = __expf(a0 - M), e1 = __expf(a1 - M);
        red[tid] = e0 + e1;
        __syncthreads();
        for (int s = NTHR / 2; s > 0; s >>= 1) {
            if (tid < s) red[tid] += red[tid + s];
            __syncthreads();
        }
        float inv = 1.0f / red[0];
        out[(size_t)bid * OUTN + tid]       = e0 * inv;
        out[(size_t)bid * OUTN + tid + 512] = e1 * inv;
    }
}

extern "C" void kernel_launch(void* const* d_in, const int* in_sizes, int n_in,
                              void* d_out, int out_size, void* d_ws, size_t ws_size,
                              hipStream_t stream) {
    (void)in_sizes; (void)n_in; (void)out_size; (void)ws_size;

    const int*   x   = (const int*)  d_in[0];
    const float* Wx1 = (const float*)d_in[1];
    const float* Wh1 = (const float*)d_in[2];
    const float* b1  = (const float*)d_in[3];
    const float* Wx2 = (const float*)d_in[4];
    const float* Wh2 = (const float*)d_in[5];
    const float* b2  = (const float*)d_in[6];
    const float* Wd  = (const float*)d_in[7];
    const float* bd  = (const float*)d_in[8];
    float* out = (float*)d_out;
    void* ws   = d_ws;

    (void)hipFuncSetAttribute((const void*)deeplog_kernel,
                              hipFuncAttributeMaxDynamicSharedMemorySize, LDS_BYTES);

    // zero: flags region (poisoned 0xAA would instantly satisfy >= tgt!) + h buffers
    size_t zero_bytes = H_OFF + (size_t)8 * BB * HH * sizeof(unsigned short);  // 1,081,344
    hipMemsetAsync(d_ws, 0, zero_bytes, stream);

    void* args[] = { &x, &Wx1, &Wh1, &b1, &Wx2, &Wh2, &b2, &Wd, &bd, &out, &ws };
    hipLaunchCooperativeKernel((const void*)deeplog_kernel,
                               dim3(NBLK), dim3(NTHR), args, LDS_BYTES, stream);
}

// Round 5
// 6059.645 us; speedup vs baseline: 3.7163x; 1.1867x over previous
//
#include <hip/hip_runtime.h>

#define BB   128   // batch
#define TT   256   // time steps
#define HH   512   // hidden
#define G4   2048  // 4*H
#define OUTN 1024  // output vocab
#define NBLK 256
#define NTHR 512

// LDS geometry
#define WSTRIDE 520                 // padded col-major stride (elems)
#define WREG    (16 * WSTRIDE)      // one weight region: 16 gate-cols x 520
#define ZOFF    (6 * WREG * 2)      // byte offset of z scratch = 99840
#define ZSTRIDE 20                  // padded z row stride (floats)
#define LDS_BYTES (ZOFF + 2 * 64 * ZSTRIDE * 4)   // 110080

// workspace layout (bytes): [4096,..) flags (u32 every 64B), [32768,..) H buffers
#define FLAG_OFF  4096
#define FLAG_STRIDE 16              // u32 elements -> 64 B apart
#define H_OFF     32768

typedef __attribute__((ext_vector_type(8))) short  v8s;   // 8 bf16 (4 VGPRs)
typedef __attribute__((ext_vector_type(4))) float  v4f;   // MFMA acc

__device__ __forceinline__ float sigmoidf_(float x) {
    return 1.0f / (1.0f + __expf(-x));
}
__device__ __forceinline__ unsigned short f2bf_rn(float f) {
    unsigned u = __float_as_uint(f);
    unsigned r = u + 0x7fffu + ((u >> 16) & 1u);
    return (unsigned short)(r >> 16);
}
__device__ __forceinline__ float bf2f(unsigned short h) {
    return __uint_as_float(((unsigned)h) << 16);
}

// Issue ALL 32 A-fragment loads (one L3 round-trip, 32-deep MLP), pin them
// before the MFMA loop with sched_barrier(0) so the compiler cannot re-sink
// them into the loop (round-4 post-mortem: VGPR=36 proved it had done so).
__device__ __forceinline__ void gemm_clustered(v4f& accP, v4f& accQ,
    const unsigned short* __restrict__ Ah, const unsigned short* __restrict__ Al,
    const unsigned short* __restrict__ Bh, const unsigned short* __restrict__ Bl)
{
    v8s ah[16], al[16];
    #pragma unroll
    for (int kk = 0; kk < 16; ++kk) {
        ah[kk] = *(const v8s*)(Ah + kk * 32);
        al[kk] = *(const v8s*)(Al + kk * 32);
    }
    __builtin_amdgcn_sched_barrier(0);
    #pragma unroll
    for (int kk = 0; kk < 16; ++kk) {
        v8s bh = *(const v8s*)(Bh + kk * 32);
        v8s bl = *(const v8s*)(Bl + kk * 32);
        accP = __builtin_amdgcn_mfma_f32_16x16x32_bf16(ah[kk], bh, accP, 0, 0, 0);
        accQ = __builtin_amdgcn_mfma_f32_16x16x32_bf16(ah[kk], bl, accQ, 0, 0, 0);
        accP = __builtin_amdgcn_mfma_f32_16x16x32_bf16(al[kk], bl, accP, 0, 0, 0);
        accQ = __builtin_amdgcn_mfma_f32_16x16x32_bf16(al[kk], bh, accQ, 0, 0, 0);
    }
}

__global__ void __launch_bounds__(NTHR, 1)
deeplog_kernel(const int* __restrict__ x,
               const float* __restrict__ Wx1, const float* __restrict__ Wh1, const float* __restrict__ b1,
               const float* __restrict__ Wx2, const float* __restrict__ Wh2, const float* __restrict__ b2,
               const float* __restrict__ Wd,  const float* __restrict__ bd,
               float* __restrict__ out, void* __restrict__ wsv)
{
    extern __shared__ char smem[];
    unsigned short* wlds = (unsigned short*)smem;            // 6 x [16][520] bf16 weight regions
    float* zlds = (float*)(smem + ZOFF);                     // [2][64][20] f32 preactivations

    char* wsb = (char*)wsv;
    unsigned* flags = (unsigned*)(wsb + FLAG_OFF);           // flag[i] at flags[i*FLAG_STRIDE]
    unsigned short* Hbase = (unsigned short*)(wsb + H_OFF);
    unsigned short* H1hi[2] = { Hbase,           Hbase + 65536 };
    unsigned short* H1lo[2] = { Hbase + 131072,  Hbase + 196608 };
    unsigned short* H2hi[2] = { Hbase + 262144,  Hbase + 327680 };
    unsigned short* H2lo[2] = { Hbase + 393216,  Hbase + 458752 };

    const int bid  = blockIdx.x;
    const int tid  = threadIdx.x;
    const int rb   = bid >> 7;           // 0..1 row-group
    const int cb   = bid & 127;          // 0..127 col-group
    const int b0   = rb * 64;            // first batch row of block
    const int n0   = cb * 4;             // first hidden unit of block
    const int fbase = rb << 7;           // flag base of my barrier group (0 or 128)

    const int lane = tid & 63;
    const int wv   = tid >> 6;           // wave 0..7
    const int isL2 = (wv >= 4);          // waves 4-7 -> layer 2
    const int wt   = isL2 ? (wv - 4) : wv;       // row-tile within block (16 rows each)
    const int kgrp = (lane >> 4) * 8;            // k-slot group for A/B fragments
    const int colb = (lane & 15) * WSTRIDE + kgrp;
    const int aoff = ((b0 + wt * 16 + (lane & 15)) << 9) + kgrp;  // row*512 + kgrp

    // gate-stage ownership: thread t -> layer (t>>8), cell (row=(t&255)>>2, nl=t&3)
    const int Lme  = tid >> 8;           // == isL2
    const int u    = tid & 255;
    const int grow = u >> 2;             // 0..63 local row
    const int nl   = u & 3;
    const int rowg = b0 + grow;          // global batch row
    const int n    = n0 + nl;            // global hidden unit

    // ---- one-time: stage split-bf16 weights to LDS (col-major, padded) ----
    for (int m = 0; m < 3; ++m) {
        const float* Wsrc = (m == 0) ? Wh1 : (m == 1) ? Wx2 : Wh2;
        unsigned short* dhi = wlds + (2 * m) * WREG;
        unsigned short* dlo = wlds + (2 * m + 1) * WREG;
        for (int i = tid; i < 8192; i += NTHR) {
            int k = i >> 4, c = i & 15;
            float v = Wsrc[(size_t)k * G4 + ((c >> 2) << 9) + n0 + (c & 3)];
            unsigned short hi = f2bf_rn(v);
            unsigned short lo = f2bf_rn(v - bf2f(hi));
            dhi[c * WSTRIDE + k] = hi;
            dlo[c * WSTRIDE + k] = lo;
        }
    }
    __syncthreads();

    const unsigned short* wh1h = wlds;
    const unsigned short* wh1l = wlds + WREG;
    const unsigned short* wx2h = wlds + 2 * WREG;
    const unsigned short* wx2l = wlds + 3 * WREG;
    const unsigned short* wh2h = wlds + 4 * WREG;
    const unsigned short* wh2l = wlds + 5 * WREG;

    // hoisted biases for owned cell (gate order i,f,g,o)
    const float* bsrc = Lme ? b2 : b1;
    float bias0 = bsrc[n], bias1 = bsrc[HH + n], bias2 = bsrc[2 * HH + n], bias3 = bsrc[3 * HH + n];

    float c_state = 0.0f;
    unsigned tgt = 1;

    #pragma unroll 1
    for (int p = 0; p <= TT; ++p) {
        // prefetch one-hot row of Wx1 for the gate stage (long slack before use)
        float wx0 = 0.f, wx1v = 0.f, wx2v = 0.f, wx3v = 0.f;
        if (Lme == 0 && p < TT) {
            int xr = x[rowg * TT + p];
            const float* wxp = Wx1 + (size_t)xr * G4 + n;
            wx0 = wxp[0]; wx1v = wxp[HH]; wx2v = wxp[2 * HH]; wx3v = wxp[3 * HH];
        }

        // ---- MFMA GEMMs ----
        const int q1 = (p - 1) & 1;   // parity holding h1(p-1)
        const int q2 = p & 1;         // parity holding h2(p-2)
        if (!isL2) {
            if (p < TT) {
                v4f accP = {0.f, 0.f, 0.f, 0.f}, accQ = {0.f, 0.f, 0.f, 0.f};
                gemm_clustered(accP, accQ, H1hi[q1] + aoff, H1lo[q1] + aoff, wh1h + colb, wh1l + colb);
                int r0 = wt * 16 + ((lane >> 4) << 2);
                #pragma unroll
                for (int q = 0; q < 4; ++q)
                    zlds[(r0 + q) * ZSTRIDE + (lane & 15)] = accP[q] + accQ[q];
            }
        } else {
            if (p >= 1) {
                v4f accP = {0.f, 0.f, 0.f, 0.f}, accQ = {0.f, 0.f, 0.f, 0.f};
                gemm_clustered(accP, accQ, H1hi[q1] + aoff, H1lo[q1] + aoff, wx2h + colb, wx2l + colb);
                __builtin_amdgcn_sched_barrier(0);   // keep gemm2's loads after gemm1 (VGPR cap)
                gemm_clustered(accP, accQ, H2hi[q2] + aoff, H2lo[q2] + aoff, wh2h + colb, wh2l + colb);
                int r0 = wt * 16 + ((lane >> 4) << 2);
                #pragma unroll
                for (int q = 0; q < 4; ++q)
                    zlds[64 * ZSTRIDE + (r0 + q) * ZSTRIDE + (lane & 15)] = accP[q] + accQ[q];
            }
        }
        __syncthreads();

        // ---- gates: thread owns one (layer, row, n) cell; c-state in register ----
        bool act = (Lme == 0) ? (p < TT) : (p >= 1);
        if (act) {
            const float* zrow = zlds + Lme * (64 * ZSTRIDE) + grow * ZSTRIDE;
            float z0 = zrow[nl]      + bias0;
            float z1 = zrow[4 + nl]  + bias1;
            float z2 = zrow[8 + nl]  + bias2;
            float z3 = zrow[12 + nl] + bias3;
            if (Lme == 0) { z0 += wx0; z1 += wx1v; z2 += wx2v; z3 += wx3v; }
            float gi = sigmoidf_(z0);
            float gf = sigmoidf_(z1);
            float gg = tanhf(z2);
            float go = sigmoidf_(z3);
            c_state  = gf * c_state + gi * gg;
            float h  = go * tanhf(c_state);
            unsigned short hhi = f2bf_rn(h);
            unsigned short hlo = f2bf_rn(h - bf2f(hhi));
            size_t hoff = (size_t)rowg * HH + n;
            if (Lme == 0) { H1hi[p & 1][hoff] = hhi;       H1lo[p & 1][hoff] = hlo; }
            else          { H2hi[(p - 1) & 1][hoff] = hhi; H2lo[(p - 1) & 1][hoff] = hlo; }
        }

        // ---- flag-array grid barrier, SPLIT BY ROW-GROUP ----
        // rb=0 and rb=1 sub-grids exchange no data (h rows stay in-group; K-dim
        // spans cols = all cb of the SAME rb) -> independent 128-flag barriers.
        // Full 256-flag barrier only at p==TT (dense head reads all rows).
        __syncthreads();
        if (tid == 0)
            __hip_atomic_store(&flags[bid * FLAG_STRIDE], tgt,
                               __ATOMIC_RELEASE, __HIP_MEMORY_SCOPE_AGENT);
        {
            const int nf = (p == TT) ? NBLK : 128;
            const int f0 = (p == TT) ? 0    : fbase;
            if (tid < nf) {
                while (__hip_atomic_load(&flags[(f0 + tid) * FLAG_STRIDE],
                                         __ATOMIC_RELAXED, __HIP_MEMORY_SCOPE_AGENT) < tgt)
                    __builtin_amdgcn_s_sleep(1);
            }
        }
        __syncthreads();
        // one acquire per block: invalidate L1/L2 so next phase's h reads see remote data
        if (tid == 0)
            (void)__hip_atomic_load(&flags[bid * FLAG_STRIDE],
                                    __ATOMIC_ACQUIRE, __HIP_MEMORY_SCOPE_AGENT);
        ++tgt;
        __syncthreads();
    }

    // ---- final dense + softmax: block b handles output row b ----
    if (bid < BB) {
        const unsigned short* h2hi = H2hi[(TT - 1) & 1] + (size_t)bid * HH;
        const unsigned short* h2lo = H2lo[(TT - 1) & 1] + (size_t)bid * HH;
        float* hrow = zlds;            // 512 floats
        float* red  = zlds + HH;       // 512 floats
        hrow[tid] = bf2f(h2hi[tid]) + bf2f(h2lo[tid]);
        __syncthreads();

        float a0 = bd[tid], a1 = bd[tid + 512];
        const float* w = Wd + tid;
        #pragma unroll 4
        for (int k = 0; k < HH; ++k) {
            float hv = hrow[k];
            a0 += hv * w[(size_t)k * OUTN];
            a1 += hv * w[(size_t)k * OUTN + 512];
        }

        red[tid] = fmaxf(a0, a1);
        __syncthreads();
        for (int s = NTHR / 2; s > 0; s >>= 1) {
            if (tid < s) red[tid] = fmaxf(red[tid], red[tid + s]);
            __syncthreads();
        }
        float M = red[0];
        __syncthreads();
        float e0 = __expf(a0 - M), e1 = __expf(a1 - M);
        red[tid] = e0 + e1;
        __syncthreads();
        for (int s = NTHR / 2; s > 0; s >>= 1) {
            if (tid < s) red[tid] += red[tid + s];
            __syncthreads();
        }
        float inv = 1.0f / red[0];
        out[(size_t)bid * OUTN + tid]       = e0 * inv;
        out[(size_t)bid * OUTN + tid + 512] = e1 * inv;
    }
}

extern "C" void kernel_launch(void* const* d_in, const int* in_sizes, int n_in,
                              void* d_out, int out_size, void* d_ws, size_t ws_size,
                              hipStream_t stream) {
    (void)in_sizes; (void)n_in; (void)out_size; (void)ws_size;

    const int*   x   = (const int*)  d_in[0];
    const float* Wx1 = (const float*)d_in[1];
    const float* Wh1 = (const float*)d_in[2];
    const float* b1  = (const float*)d_in[3];
    const float* Wx2 = (const float*)d_in[4];
    const float* Wh2 = (const float*)d_in[5];
    const float* b2  = (const float*)d_in[6];
    const float* Wd  = (const float*)d_in[7];
    const float* bd  = (const float*)d_in[8];
    float* out = (float*)d_out;
    void* ws   = d_ws;

    (void)hipFuncSetAttribute((const void*)deeplog_kernel,
                              hipFuncAttributeMaxDynamicSharedMemorySize, LDS_BYTES);

    // zero: flags region (poisoned 0xAA would instantly satisfy >= tgt!) + h buffers
    size_t zero_bytes = H_OFF + (size_t)8 * BB * HH * sizeof(unsigned short);  // 1,081,344
    hipMemsetAsync(d_ws, 0, zero_bytes, stream);

    void* args[] = { &x, &Wx1, &Wh1, &b1, &Wx2, &Wh2, &b2, &Wd, &bd, &out, &ws };
    hipLaunchCooperativeKernel((const void*)deeplog_kernel,
                               dim3(NBLK), dim3(NTHR), args, LDS_BYTES, stream);
}

// Round 6
// 4310.166 us; speedup vs baseline: 5.2248x; 1.4059x over previous
//
#include <hip/hip_runtime.h>

#define BB   128   // batch
#define TT   256   // time steps
#define HH   512   // hidden
#define G4   2048  // 4*H
#define OUTN 1024  // output vocab
#define NBLK 256
#define NTHR 512

// LDS geometry
#define WSTRIDE 520                 // padded col-major stride (elems)
#define WREG    (16 * WSTRIDE)      // one weight region: 16 gate-cols x 520
#define ZOFF    (6 * WREG * 2)      // byte offset of z scratch = 99840
#define ZSTRIDE 20                  // padded z row stride (floats)
#define LDS_BYTES (ZOFF + 2 * 64 * ZSTRIDE * 4)   // 110080

// workspace layout (bytes): [4096,..) flags (u32 every 64B), [32768,..) H buffers
#define FLAG_OFF  4096
#define FLAG_STRIDE 16              // u32 elements -> 64 B apart
#define H_OFF     32768

typedef __attribute__((ext_vector_type(8))) short  v8s;   // 8 bf16 (4 VGPRs)
typedef __attribute__((ext_vector_type(4))) float  v4f;   // MFMA acc

__device__ __forceinline__ float sigmoidf_(float x) {
    return 1.0f / (1.0f + __expf(-x));
}
__device__ __forceinline__ unsigned short f2bf_rn(float f) {
    unsigned u = __float_as_uint(f);
    unsigned r = u + 0x7fffu + ((u >> 16) & 1u);
    return (unsigned short)(r >> 16);
}
__device__ __forceinline__ float bf2f(unsigned short h) {
    return __uint_as_float(((unsigned)h) << 16);
}

// Issue ALL 32 A-fragment loads, then FORCE them live-in-registers with an
// empty asm that consumes each value (round-5 post-mortem: sched_barrier alone
// was defeated, VGPR=96 < the 128 needed). Then one waitcnt, then 64 MFMAs.
__device__ __forceinline__ void gemm_clustered(v4f& accP, v4f& accQ,
    const unsigned short* __restrict__ Ah, const unsigned short* __restrict__ Al,
    const unsigned short* __restrict__ Bh, const unsigned short* __restrict__ Bl)
{
    v8s ah[16], al[16];
    #pragma unroll
    for (int kk = 0; kk < 16; ++kk) {
        ah[kk] = *(const v8s*)(Ah + kk * 32);
        al[kk] = *(const v8s*)(Al + kk * 32);
    }
    #pragma unroll
    for (int kk = 0; kk < 16; ++kk)
        asm volatile("" : "+v"(ah[kk]), "+v"(al[kk]));   // pin: loads cannot sink past this
    __builtin_amdgcn_sched_barrier(0);
    #pragma unroll
    for (int kk = 0; kk < 16; ++kk) {
        v8s bh = *(const v8s*)(Bh + kk * 32);
        v8s bl = *(const v8s*)(Bl + kk * 32);
        accP = __builtin_amdgcn_mfma_f32_16x16x32_bf16(ah[kk], bh, accP, 0, 0, 0);
        accQ = __builtin_amdgcn_mfma_f32_16x16x32_bf16(ah[kk], bl, accQ, 0, 0, 0);
        accP = __builtin_amdgcn_mfma_f32_16x16x32_bf16(al[kk], bl, accP, 0, 0, 0);
        accQ = __builtin_amdgcn_mfma_f32_16x16x32_bf16(al[kk], bh, accQ, 0, 0, 0);
    }
}

__global__ void __launch_bounds__(NTHR, 1)
deeplog_kernel(const int* __restrict__ x,
               const float* __restrict__ Wx1, const float* __restrict__ Wh1, const float* __restrict__ b1,
               const float* __restrict__ Wx2, const float* __restrict__ Wh2, const float* __restrict__ b2,
               const float* __restrict__ Wd,  const float* __restrict__ bd,
               float* __restrict__ out, void* __restrict__ wsv)
{
    extern __shared__ char smem[];
    unsigned short* wlds = (unsigned short*)smem;            // 6 x [16][520] bf16 weight regions
    float* zlds = (float*)(smem + ZOFF);                     // [2][64][20] f32 preactivations

    char* wsb = (char*)wsv;
    unsigned* flags = (unsigned*)(wsb + FLAG_OFF);           // flag[i] at flags[i*FLAG_STRIDE]
    unsigned short* Hbase = (unsigned short*)(wsb + H_OFF);
    unsigned short* H1hi[2] = { Hbase,           Hbase + 65536 };
    unsigned short* H1lo[2] = { Hbase + 131072,  Hbase + 196608 };
    unsigned short* H2hi[2] = { Hbase + 262144,  Hbase + 327680 };
    unsigned short* H2lo[2] = { Hbase + 393216,  Hbase + 458752 };
    // u32 views for pair-packed write-through stores (same memory, same layout)
    unsigned* H1hi32[2] = { (unsigned*)H1hi[0], (unsigned*)H1hi[1] };
    unsigned* H1lo32[2] = { (unsigned*)H1lo[0], (unsigned*)H1lo[1] };
    unsigned* H2hi32[2] = { (unsigned*)H2hi[0], (unsigned*)H2hi[1] };
    unsigned* H2lo32[2] = { (unsigned*)H2lo[0], (unsigned*)H2lo[1] };

    const int bid  = blockIdx.x;
    const int tid  = threadIdx.x;
    const int rb   = bid >> 7;           // 0..1 row-group
    const int cb   = bid & 127;          // 0..127 col-group
    const int b0   = rb * 64;            // first batch row of block
    const int n0   = cb * 4;             // first hidden unit of block
    const int fbase = rb << 7;           // flag base of my barrier group (0 or 128)

    const int lane = tid & 63;
    const int wv   = tid >> 6;           // wave 0..7
    const int isL2 = (wv >= 4);          // waves 4-7 -> layer 2
    const int wt   = isL2 ? (wv - 4) : wv;       // row-tile within block (16 rows each)
    const int kgrp = (lane >> 4) * 8;            // k-slot group for A/B fragments
    const int colb = (lane & 15) * WSTRIDE + kgrp;
    const int aoff = ((b0 + wt * 16 + (lane & 15)) << 9) + kgrp;  // row*512 + kgrp

    // gate-stage ownership: thread t -> layer (t>>8), cell (row=(t&255)>>2, nl=t&3)
    const int Lme  = tid >> 8;           // == isL2
    const int u    = tid & 255;
    const int grow = u >> 2;             // 0..63 local row
    const int nl   = u & 3;
    const int rowg = b0 + grow;          // global batch row
    const int n    = n0 + nl;            // global hidden unit

    // ---- one-time: stage split-bf16 weights to LDS (col-major, padded) ----
    for (int m = 0; m < 3; ++m) {
        const float* Wsrc = (m == 0) ? Wh1 : (m == 1) ? Wx2 : Wh2;
        unsigned short* dhi = wlds + (2 * m) * WREG;
        unsigned short* dlo = wlds + (2 * m + 1) * WREG;
        for (int i = tid; i < 8192; i += NTHR) {
            int k = i >> 4, c = i & 15;
            float v = Wsrc[(size_t)k * G4 + ((c >> 2) << 9) + n0 + (c & 3)];
            unsigned short hi = f2bf_rn(v);
            unsigned short lo = f2bf_rn(v - bf2f(hi));
            dhi[c * WSTRIDE + k] = hi;
            dlo[c * WSTRIDE + k] = lo;
        }
    }
    __syncthreads();

    const unsigned short* wh1h = wlds;
    const unsigned short* wh1l = wlds + WREG;
    const unsigned short* wx2h = wlds + 2 * WREG;
    const unsigned short* wx2l = wlds + 3 * WREG;
    const unsigned short* wh2h = wlds + 4 * WREG;
    const unsigned short* wh2l = wlds + 5 * WREG;

    // hoisted biases for owned cell (gate order i,f,g,o)
    const float* bsrc = Lme ? b2 : b1;
    float bias0 = bsrc[n], bias1 = bsrc[HH + n], bias2 = bsrc[2 * HH + n], bias3 = bsrc[3 * HH + n];

    float c_state = 0.0f;
    unsigned tgt = 1;

    #pragma unroll 1
    for (int p = 0; p <= TT; ++p) {
        // prefetch one-hot row of Wx1 for the gate stage (long slack before use)
        float wx0 = 0.f, wx1v = 0.f, wx2v = 0.f, wx3v = 0.f;
        if (Lme == 0 && p < TT) {
            int xr = x[rowg * TT + p];
            const float* wxp = Wx1 + (size_t)xr * G4 + n;
            wx0 = wxp[0]; wx1v = wxp[HH]; wx2v = wxp[2 * HH]; wx3v = wxp[3 * HH];
        }

        // ---- MFMA GEMMs (A from global, cached: L2 filters the K-dim re-read;
        // freshness guaranteed by the per-phase acquire-inv below) ----
        const int q1 = (p - 1) & 1;   // parity holding h1(p-1)
        const int q2 = p & 1;         // parity holding h2(p-2)
        if (!isL2) {
            if (p < TT) {
                v4f accP = {0.f, 0.f, 0.f, 0.f}, accQ = {0.f, 0.f, 0.f, 0.f};
                gemm_clustered(accP, accQ, H1hi[q1] + aoff, H1lo[q1] + aoff, wh1h + colb, wh1l + colb);
                int r0 = wt * 16 + ((lane >> 4) << 2);
                #pragma unroll
                for (int q = 0; q < 4; ++q)
                    zlds[(r0 + q) * ZSTRIDE + (lane & 15)] = accP[q] + accQ[q];
            }
        } else {
            if (p >= 1) {
                v4f accP = {0.f, 0.f, 0.f, 0.f}, accQ = {0.f, 0.f, 0.f, 0.f};
                gemm_clustered(accP, accQ, H1hi[q1] + aoff, H1lo[q1] + aoff, wx2h + colb, wx2l + colb);
                __builtin_amdgcn_sched_barrier(0);   // keep gemm2's loads after gemm1 (VGPR cap)
                gemm_clustered(accP, accQ, H2hi[q2] + aoff, H2lo[q2] + aoff, wh2h + colb, wh2l + colb);
                int r0 = wt * 16 + ((lane >> 4) << 2);
                #pragma unroll
                for (int q = 0; q < 4; ++q)
                    zlds[64 * ZSTRIDE + (r0 + q) * ZSTRIDE + (lane & 15)] = accP[q] + accQ[q];
            }
        }
        __syncthreads();

        // ---- gates: thread owns one (layer, row, n) cell; c-state in register.
        // h published as WRITE-THROUGH agent atomics (u32 = two adjacent n) so the
        // XCD L2 never holds dirty recurrent data -> no wbl2 needed at release. ----
        bool act = (Lme == 0) ? (p < TT) : (p >= 1);
        if (act) {
            const float* zrow = zlds + Lme * (64 * ZSTRIDE) + grow * ZSTRIDE;
            float z0 = zrow[nl]      + bias0;
            float z1 = zrow[4 + nl]  + bias1;
            float z2 = zrow[8 + nl]  + bias2;
            float z3 = zrow[12 + nl] + bias3;
            if (Lme == 0) { z0 += wx0; z1 += wx1v; z2 += wx2v; z3 += wx3v; }
            float gi = sigmoidf_(z0);
            float gf = sigmoidf_(z1);
            float gg = tanhf(z2);
            float go = sigmoidf_(z3);
            c_state  = gf * c_state + gi * gg;
            float h  = go * tanhf(c_state);
            unsigned hhi = f2bf_rn(h);
            unsigned hlo = f2bf_rn(h - bf2f((unsigned short)hhi));
            // pair with neighbor n^1 (adjacent lane, same wave; act is wave-uniform)
            unsigned ph = (unsigned)__shfl_xor((int)hhi, 1, 64);
            unsigned pl = (unsigned)__shfl_xor((int)hlo, 1, 64);
            if ((nl & 1) == 0) {
                unsigned hw = (hhi & 0xffffu) | (ph << 16);   // low half = even n
                unsigned lw = (hlo & 0xffffu) | (pl << 16);
                unsigned *dsthi, *dstlo;
                if (Lme == 0) { dsthi = H1hi32[p & 1];       dstlo = H1lo32[p & 1]; }
                else          { dsthi = H2hi32[(p - 1) & 1]; dstlo = H2lo32[(p - 1) & 1]; }
                int idx = rowg * 256 + (n >> 1);
                __hip_atomic_store(dsthi + idx, hw, __ATOMIC_RELAXED, __HIP_MEMORY_SCOPE_AGENT);
                __hip_atomic_store(dstlo + idx, lw, __ATOMIC_RELAXED, __HIP_MEMORY_SCOPE_AGENT);
            }
        }

        // ---- flag-array grid barrier, split by row-group; NO wbl2 anywhere ----
        // arrival: syncthreads drains every thread's vmcnt (write-through stores are
        // then L3-visible); pin with explicit waitcnt, then RELAXED flag store.
        __syncthreads();
        if (tid == 0) {
            asm volatile("s_waitcnt vmcnt(0)" ::: "memory");
            __hip_atomic_store(&flags[bid * FLAG_STRIDE], tgt,
                               __ATOMIC_RELAXED, __HIP_MEMORY_SCOPE_AGENT);
        }
        {
            const int nf = (p == TT) ? NBLK : 128;
            const int f0 = (p == TT) ? 0    : fbase;
            if (tid < nf) {
                while (__hip_atomic_load(&flags[(f0 + tid) * FLAG_STRIDE],
                                         __ATOMIC_RELAXED, __HIP_MEMORY_SCOPE_AGENT) < tgt)
                    __builtin_amdgcn_s_sleep(1);
            }
        }
        __syncthreads();
        // one acquire per block: invalidate L1/L2 so next phase's cached h reads refetch
        if (tid == 0)
            (void)__hip_atomic_load(&flags[bid * FLAG_STRIDE],
                                    __ATOMIC_ACQUIRE, __HIP_MEMORY_SCOPE_AGENT);
        ++tgt;
        __syncthreads();
    }

    // ---- final dense + softmax: block b handles output row b ----
    if (bid < BB) {
        const unsigned short* h2hi = H2hi[(TT - 1) & 1] + (size_t)bid * HH;
        const unsigned short* h2lo = H2lo[(TT - 1) & 1] + (size_t)bid * HH;
        float* hrow = zlds;            // 512 floats
        float* red  = zlds + HH;       // 512 floats
        hrow[tid] = bf2f(h2hi[tid]) + bf2f(h2lo[tid]);
        __syncthreads();

        float a0 = bd[tid], a1 = bd[tid + 512];
        const float* w = Wd + tid;
        #pragma unroll 4
        for (int k = 0; k < HH; ++k) {
            float hv = hrow[k];
            a0 += hv * w[(size_t)k * OUTN];
            a1 += hv * w[(size_t)k * OUTN + 512];
        }

        red[tid] = fmaxf(a0, a1);
        __syncthreads();
        for (int s = NTHR / 2; s > 0; s >>= 1) {
            if (tid < s) red[tid] = fmaxf(red[tid], red[tid + s]);
            __syncthreads();
        }
        float M = red[0];
        __syncthreads();
        float e0 = __expf(a0 - M), e1 = __expf(a1 - M);
        red[tid] = e0 + e1;
        __syncthreads();
        for (int s = NTHR / 2; s > 0; s >>= 1) {
            if (tid < s) red[tid] += red[tid + s];
            __syncthreads();
        }
        float inv = 1.0f / red[0];
        out[(size_t)bid * OUTN + tid]       = e0 * inv;
        out[(size_t)bid * OUTN + tid + 512] = e1 * inv;
    }
}

extern "C" void kernel_launch(void* const* d_in, const int* in_sizes, int n_in,
                              void* d_out, int out_size, void* d_ws, size_t ws_size,
                              hipStream_t stream) {
    (void)in_sizes; (void)n_in; (void)out_size; (void)ws_size;

    const int*   x   = (const int*)  d_in[0];
    const float* Wx1 = (const float*)d_in[1];
    const float* Wh1 = (const float*)d_in[2];
    const float* b1  = (const float*)d_in[3];
    const float* Wx2 = (const float*)d_in[4];
    const float* Wh2 = (const float*)d_in[5];
    const float* b2  = (const float*)d_in[6];
    const float* Wd  = (const float*)d_in[7];
    const float* bd  = (const float*)d_in[8];
    float* out = (float*)d_out;
    void* ws   = d_ws;

    (void)hipFuncSetAttribute((const void*)deeplog_kernel,
                              hipFuncAttributeMaxDynamicSharedMemorySize, LDS_BYTES);

    // zero: flags region (poisoned 0xAA would instantly satisfy >= tgt!) + h buffers
    size_t zero_bytes = H_OFF + (size_t)8 * BB * HH * sizeof(unsigned short);  // 1,081,344
    hipMemsetAsync(d_ws, 0, zero_bytes, stream);

    void* args[] = { &x, &Wx1, &Wh1, &b1, &Wx2, &Wh2, &b2, &Wd, &bd, &out, &ws };
    hipLaunchCooperativeKernel((const void*)deeplog_kernel,
                               dim3(NBLK), dim3(NTHR), args, LDS_BYTES, stream);
}

// Round 7
// 4201.613 us; speedup vs baseline: 5.3597x; 1.0258x over previous
//
#include <hip/hip_runtime.h>

#define BB   128   // batch
#define TT   256   // time steps
#define HH   512   // hidden
#define G4   2048  // 4*H
#define OUTN 1024  // output vocab
#define NBLK 256
#define NTHR 512

// LDS geometry
#define WSTRIDE 520                 // padded col-major stride (elems)
#define WREG    (16 * WSTRIDE)      // one weight region: 16 gate-cols x 520
#define ZOFF    (6 * WREG * 2)      // byte offset of z scratch = 99840
#define ZSTRIDE 20                  // padded z row stride (floats)
#define LDS_BYTES (ZOFF + 2 * 64 * ZSTRIDE * 4)   // 110080

// workspace layout (bytes): [4096,..) flags (u32 every 64B), [32768,..) H buffers
#define FLAG_OFF  4096
#define FLAG_STRIDE 16              // u32 elements -> 64 B apart
#define H_OFF     32768

typedef __attribute__((ext_vector_type(8))) short  v8s;   // 8 bf16 (4 VGPRs)
typedef __attribute__((ext_vector_type(4))) float  v4f;   // MFMA acc

#define MFMA_(a,b,c) __builtin_amdgcn_mfma_f32_16x16x32_bf16(a, b, c, 0, 0, 0)

__device__ __forceinline__ float sigmoidf_(float x) {
    return 1.0f / (1.0f + __expf(-x));
}
__device__ __forceinline__ unsigned short f2bf_rn(float f) {
    unsigned u = __float_as_uint(f);
    unsigned r = u + 0x7fffu + ((u >> 16) & 1u);
    return (unsigned short)(r >> 16);
}
__device__ __forceinline__ float bf2f(unsigned short h) {
    return __uint_as_float(((unsigned)h) << 16);
}

// Issue 16 x global_load_dwordx4 as REAL asm loads: the compiler cannot sink,
// split, or scratch-spill them (round-5/6 post-mortems: source-level prefetch
// was defeated twice; VGPR=92 < the 128 a true prefetch needs).
__device__ __forceinline__ void issue16(v8s f[16], const unsigned short* base) {
    #pragma unroll
    for (int kk = 0; kk < 16; ++kk)
        asm volatile("global_load_dwordx4 %0, %1, off"
                     : "=v"(f[kk]) : "v"(base + kk * 32) : "memory");
}
#define WAITCNT_VM(N) do { \
    asm volatile("s_waitcnt vmcnt(" #N ")" ::: "memory"); \
    __builtin_amdgcn_sched_barrier(0); \
} while (0)

// all 4 split products: accP += ah*bh + al*bl ; accQ += ah*bl + al*bh
__device__ __forceinline__ void mfma16_full(v4f& accP, v4f& accQ,
    const v8s ah[16], const v8s al[16],
    const unsigned short* __restrict__ Bh, const unsigned short* __restrict__ Bl)
{
    #pragma unroll
    for (int kk = 0; kk < 16; ++kk) {
        v8s bh = *(const v8s*)(Bh + kk * 32);
        v8s bl = *(const v8s*)(Bl + kk * 32);
        accP = MFMA_(ah[kk], bh, accP);
        accQ = MFMA_(ah[kk], bl, accQ);
        accP = MFMA_(al[kk], bl, accP);
        accQ = MFMA_(al[kk], bh, accQ);
    }
}
// hi-half products only (a-hi against both B splits)
__device__ __forceinline__ void mfma16_h(v4f& accP, v4f& accQ, const v8s ah[16],
    const unsigned short* __restrict__ Bh, const unsigned short* __restrict__ Bl)
{
    #pragma unroll
    for (int kk = 0; kk < 16; ++kk) {
        v8s bh = *(const v8s*)(Bh + kk * 32);
        v8s bl = *(const v8s*)(Bl + kk * 32);
        accP = MFMA_(ah[kk], bh, accP);
        accQ = MFMA_(ah[kk], bl, accQ);
    }
}
// lo-half products only
__device__ __forceinline__ void mfma16_l(v4f& accP, v4f& accQ, const v8s al[16],
    const unsigned short* __restrict__ Bh, const unsigned short* __restrict__ Bl)
{
    #pragma unroll
    for (int kk = 0; kk < 16; ++kk) {
        v8s bh = *(const v8s*)(Bh + kk * 32);
        v8s bl = *(const v8s*)(Bl + kk * 32);
        accP = MFMA_(al[kk], bl, accP);
        accQ = MFMA_(al[kk], bh, accQ);
    }
}

__global__ void __launch_bounds__(NTHR, 1)
deeplog_kernel(const int* __restrict__ x,
               const float* __restrict__ Wx1, const float* __restrict__ Wh1, const float* __restrict__ b1,
               const float* __restrict__ Wx2, const float* __restrict__ Wh2, const float* __restrict__ b2,
               const float* __restrict__ Wd,  const float* __restrict__ bd,
               float* __restrict__ out, void* __restrict__ wsv)
{
    extern __shared__ char smem[];
    unsigned short* wlds = (unsigned short*)smem;            // 6 x [16][520] bf16 weight regions
    float* zlds = (float*)(smem + ZOFF);                     // [2][64][20] f32 preactivations

    char* wsb = (char*)wsv;
    unsigned* flags = (unsigned*)(wsb + FLAG_OFF);           // flag[i] at flags[i*FLAG_STRIDE]
    unsigned short* Hbase = (unsigned short*)(wsb + H_OFF);
    unsigned short* H1hi[2] = { Hbase,           Hbase + 65536 };
    unsigned short* H1lo[2] = { Hbase + 131072,  Hbase + 196608 };
    unsigned short* H2hi[2] = { Hbase + 262144,  Hbase + 327680 };
    unsigned short* H2lo[2] = { Hbase + 393216,  Hbase + 458752 };
    // u32 views for pair-packed write-through stores (same memory, same layout)
    unsigned* H1hi32[2] = { (unsigned*)H1hi[0], (unsigned*)H1hi[1] };
    unsigned* H1lo32[2] = { (unsigned*)H1lo[0], (unsigned*)H1lo[1] };
    unsigned* H2hi32[2] = { (unsigned*)H2hi[0], (unsigned*)H2hi[1] };
    unsigned* H2lo32[2] = { (unsigned*)H2lo[0], (unsigned*)H2lo[1] };

    const int bid  = blockIdx.x;
    const int tid  = threadIdx.x;
    const int rb   = bid >> 7;           // 0..1 row-group
    const int cb   = bid & 127;          // 0..127 col-group
    const int b0   = rb * 64;            // first batch row of block
    const int n0   = cb * 4;             // first hidden unit of block
    const int fbase = rb << 7;           // flag base of my barrier group (0 or 128)

    const int lane = tid & 63;
    const int wv   = tid >> 6;           // wave 0..7
    const int isL2 = (wv >= 4);          // waves 4-7 -> layer 2
    const int wt   = isL2 ? (wv - 4) : wv;       // row-tile within block (16 rows each)
    const int kgrp = (lane >> 4) * 8;            // k-slot group for A/B fragments
    const int colb = (lane & 15) * WSTRIDE + kgrp;
    const int aoff = ((b0 + wt * 16 + (lane & 15)) << 9) + kgrp;  // row*512 + kgrp

    // gate-stage ownership: thread t -> layer (t>>8), cell (row=(t&255)>>2, nl=t&3)
    const int Lme  = tid >> 8;           // == isL2
    const int u    = tid & 255;
    const int grow = u >> 2;             // 0..63 local row
    const int nl   = u & 3;
    const int rowg = b0 + grow;          // global batch row
    const int n    = n0 + nl;            // global hidden unit

    // ---- one-time: stage split-bf16 weights to LDS (col-major, padded) ----
    for (int m = 0; m < 3; ++m) {
        const float* Wsrc = (m == 0) ? Wh1 : (m == 1) ? Wx2 : Wh2;
        unsigned short* dhi = wlds + (2 * m) * WREG;
        unsigned short* dlo = wlds + (2 * m + 1) * WREG;
        for (int i = tid; i < 8192; i += NTHR) {
            int k = i >> 4, c = i & 15;
            float v = Wsrc[(size_t)k * G4 + ((c >> 2) << 9) + n0 + (c & 3)];
            unsigned short hi = f2bf_rn(v);
            unsigned short lo = f2bf_rn(v - bf2f(hi));
            dhi[c * WSTRIDE + k] = hi;
            dlo[c * WSTRIDE + k] = lo;
        }
    }
    __syncthreads();

    const unsigned short* wh1h = wlds;
    const unsigned short* wh1l = wlds + WREG;
    const unsigned short* wx2h = wlds + 2 * WREG;
    const unsigned short* wx2l = wlds + 3 * WREG;
    const unsigned short* wh2h = wlds + 4 * WREG;
    const unsigned short* wh2l = wlds + 5 * WREG;

    // hoisted biases for owned cell (gate order i,f,g,o)
    const float* bsrc = Lme ? b2 : b1;
    float bias0 = bsrc[n], bias1 = bsrc[HH + n], bias2 = bsrc[2 * HH + n], bias3 = bsrc[3 * HH + n];

    float c_state = 0.0f;
    unsigned tgt = 1;

    #pragma unroll 1
    for (int p = 0; p <= TT; ++p) {
        // prefetch one-hot row of Wx1 for the gate stage. L1 waves only; their
        // gemm wait is vmcnt(0), so these extra outstanding loads are safe.
        float wx0 = 0.f, wx1v = 0.f, wx2v = 0.f, wx3v = 0.f;
        if (Lme == 0 && p < TT) {
            int xr = x[rowg * TT + p];
            const float* wxp = Wx1 + (size_t)xr * G4 + n;
            wx0 = wxp[0]; wx1v = wxp[HH]; wx2v = wxp[2 * HH]; wx3v = wxp[3 * HH];
        }

        // ---- MFMA GEMMs: asm-load clusters + counted vmcnt pipeline ----
        const int q1 = (p - 1) & 1;   // parity holding h1(p-1)
        const int q2 = p & 1;         // parity holding h2(p-2)
        if (!isL2) {
            if (p < TT) {
                v4f accP = {0.f, 0.f, 0.f, 0.f}, accQ = {0.f, 0.f, 0.f, 0.f};
                v8s ah[16], al[16];
                issue16(ah, H1hi[q1] + aoff);
                issue16(al, H1lo[q1] + aoff);
                WAITCNT_VM(0);
                mfma16_full(accP, accQ, ah, al, wh1h + colb, wh1l + colb);
                int r0 = wt * 16 + ((lane >> 4) << 2);
                #pragma unroll
                for (int q = 0; q < 4; ++q)
                    zlds[(r0 + q) * ZSTRIDE + (lane & 15)] = accP[q] + accQ[q];
            }
        } else {
            if (p >= 1) {
                v4f accP = {0.f, 0.f, 0.f, 0.f}, accQ = {0.f, 0.f, 0.f, 0.f};
                v8s a1h[16], a1l[16], a2h[16], a2l[16];
                issue16(a1h, H1hi[q1] + aoff);       // 16 outstanding
                issue16(a1l, H1lo[q1] + aoff);       // 32
                issue16(a2h, H2hi[q2] + aoff);       // 48
                WAITCNT_VM(16);                      // oldest 32 (= all of g1) done
                mfma16_full(accP, accQ, a1h, a1l, wx2h + colb, wx2l + colb);  // covers a2h flight
                issue16(a2l, H2lo[q2] + aoff);       // <=32 outstanding
                WAITCNT_VM(16);                      // all a2h done
                mfma16_h(accP, accQ, a2h, wh2h + colb, wh2l + colb);
                WAITCNT_VM(0);                       // all a2l done
                mfma16_l(accP, accQ, a2l, wh2h + colb, wh2l + colb);
                int r0 = wt * 16 + ((lane >> 4) << 2);
                #pragma unroll
                for (int q = 0; q < 4; ++q)
                    zlds[64 * ZSTRIDE + (r0 + q) * ZSTRIDE + (lane & 15)] = accP[q] + accQ[q];
            }
        }
        __syncthreads();

        // ---- gates: thread owns one (layer, row, n) cell; c-state in register.
        // h published as WRITE-THROUGH agent atomics (u32 = two adjacent n) so the
        // XCD L2 never holds dirty recurrent data -> no wbl2 needed at release. ----
        bool act = (Lme == 0) ? (p < TT) : (p >= 1);
        if (act) {
            const float* zrow = zlds + Lme * (64 * ZSTRIDE) + grow * ZSTRIDE;
            float z0 = zrow[nl]      + bias0;
            float z1 = zrow[4 + nl]  + bias1;
            float z2 = zrow[8 + nl]  + bias2;
            float z3 = zrow[12 + nl] + bias3;
            if (Lme == 0) { z0 += wx0; z1 += wx1v; z2 += wx2v; z3 += wx3v; }
            float gi = sigmoidf_(z0);
            float gf = sigmoidf_(z1);
            float gg = tanhf(z2);
            float go = sigmoidf_(z3);
            c_state  = gf * c_state + gi * gg;
            float h  = go * tanhf(c_state);
            unsigned hhi = f2bf_rn(h);
            unsigned hlo = f2bf_rn(h - bf2f((unsigned short)hhi));
            // pair with neighbor n^1 (adjacent lane, same wave; act is wave-uniform)
            unsigned ph = (unsigned)__shfl_xor((int)hhi, 1, 64);
            unsigned pl = (unsigned)__shfl_xor((int)hlo, 1, 64);
            if ((nl & 1) == 0) {
                unsigned hw = (hhi & 0xffffu) | (ph << 16);   // low half = even n
                unsigned lw = (hlo & 0xffffu) | (pl << 16);
                unsigned *dsthi, *dstlo;
                if (Lme == 0) { dsthi = H1hi32[p & 1];       dstlo = H1lo32[p & 1]; }
                else          { dsthi = H2hi32[(p - 1) & 1]; dstlo = H2lo32[(p - 1) & 1]; }
                int idx = rowg * 256 + (n >> 1);
                __hip_atomic_store(dsthi + idx, hw, __ATOMIC_RELAXED, __HIP_MEMORY_SCOPE_AGENT);
                __hip_atomic_store(dstlo + idx, lw, __ATOMIC_RELAXED, __HIP_MEMORY_SCOPE_AGENT);
            }
        }

        // ---- flag-array grid barrier, split by row-group; NO wbl2 anywhere ----
        __syncthreads();
        if (tid == 0) {
            asm volatile("s_waitcnt vmcnt(0)" ::: "memory");
            __hip_atomic_store(&flags[bid * FLAG_STRIDE], tgt,
                               __ATOMIC_RELAXED, __HIP_MEMORY_SCOPE_AGENT);
        }
        {
            const int nf = (p == TT) ? NBLK : 128;
            const int f0 = (p == TT) ? 0    : fbase;
            if (tid < nf) {
                while (__hip_atomic_load(&flags[(f0 + tid) * FLAG_STRIDE],
                                         __ATOMIC_RELAXED, __HIP_MEMORY_SCOPE_AGENT) < tgt)
                    __builtin_amdgcn_s_sleep(1);
            }
        }
        __syncthreads();
        // one acquire per block: invalidate L1/L2 so next phase's cached h reads refetch
        if (tid == 0)
            (void)__hip_atomic_load(&flags[bid * FLAG_STRIDE],
                                    __ATOMIC_ACQUIRE, __HIP_MEMORY_SCOPE_AGENT);
        ++tgt;
        __syncthreads();
    }

    // ---- final dense + softmax: block b handles output row b ----
    if (bid < BB) {
        const unsigned short* h2hi = H2hi[(TT - 1) & 1] + (size_t)bid * HH;
        const unsigned short* h2lo = H2lo[(TT - 1) & 1] + (size_t)bid * HH;
        float* hrow = zlds;            // 512 floats
        float* red  = zlds + HH;       // 512 floats
        hrow[tid] = bf2f(h2hi[tid]) + bf2f(h2lo[tid]);
        __syncthreads();

        float a0 = bd[tid], a1 = bd[tid + 512];
        const float* w = Wd + tid;
        #pragma unroll 4
        for (int k = 0; k < HH; ++k) {
            float hv = hrow[k];
            a0 += hv * w[(size_t)k * OUTN];
            a1 += hv * w[(size_t)k * OUTN + 512];
        }

        red[tid] = fmaxf(a0, a1);
        __syncthreads();
        for (int s = NTHR / 2; s > 0; s >>= 1) {
            if (tid < s) red[tid] = fmaxf(red[tid], red[tid + s]);
            __syncthreads();
        }
        float M = red[0];
        __syncthreads();
        float e0 = __expf(a0 - M), e1 = __expf(a1 - M);
        red[tid] = e0 + e1;
        __syncthreads();
        for (int s = NTHR / 2; s > 0; s >>= 1) {
            if (tid < s) red[tid] += red[tid + s];
            __syncthreads();
        }
        float inv = 1.0f / red[0];
        out[(size_t)bid * OUTN + tid]       = e0 * inv;
        out[(size_t)bid * OUTN + tid + 512] = e1 * inv;
    }
}

extern "C" void kernel_launch(void* const* d_in, const int* in_sizes, int n_in,
                              void* d_out, int out_size, void* d_ws, size_t ws_size,
                              hipStream_t stream) {
    (void)in_sizes; (void)n_in; (void)out_size; (void)ws_size;

    const int*   x   = (const int*)  d_in[0];
    const float* Wx1 = (const float*)d_in[1];
    const float* Wh1 = (const float*)d_in[2];
    const float* b1  = (const float*)d_in[3];
    const float* Wx2 = (const float*)d_in[4];
    const float* Wh2 = (const float*)d_in[5];
    const float* b2  = (const float*)d_in[6];
    const float* Wd  = (const float*)d_in[7];
    const float* bd  = (const float*)d_in[8];
    float* out = (float*)d_out;
    void* ws   = d_ws;

    (void)hipFuncSetAttribute((const void*)deeplog_kernel,
                              hipFuncAttributeMaxDynamicSharedMemorySize, LDS_BYTES);

    // zero: flags region (poisoned 0xAA would instantly satisfy >= tgt!) + h buffers
    size_t zero_bytes = H_OFF + (size_t)8 * BB * HH * sizeof(unsigned short);  // 1,081,344
    hipMemsetAsync(d_ws, 0, zero_bytes, stream);

    void* args[] = { &x, &Wx1, &Wh1, &b1, &Wx2, &Wh2, &b2, &Wd, &bd, &out, &ws };
    hipLaunchCooperativeKernel((const void*)deeplog_kernel,
                               dim3(NBLK), dim3(NTHR), args, LDS_BYTES, stream);
}

// Round 8
// 4170.428 us; speedup vs baseline: 5.3998x; 1.0075x over previous
//
#include <hip/hip_runtime.h>

#define BB   128   // batch
#define TT   256   // time steps
#define HH   512   // hidden
#define G4   2048  // 4*H
#define OUTN 1024  // output vocab
#define NBLK 256
#define NTHR 512

// LDS geometry
#define WSTRIDE 520                 // padded col-major stride (elems)
#define WREG    (16 * WSTRIDE)      // one weight region: 16 gate-cols x 520
#define ZOFF    (6 * WREG * 2)      // byte offset of z scratch = 99840
#define ZSTRIDE 20                  // padded z row stride (floats)
#define LDS_BYTES (ZOFF + 2 * 64 * ZSTRIDE * 4)   // 110080

// workspace layout (bytes): [4096,..) flags (u32 every 64B), [32768,..) H buffers
#define FLAG_OFF  4096
#define FLAG_STRIDE 16              // u32 elements -> 64 B apart
#define H_OFF     32768

typedef __attribute__((ext_vector_type(8))) short  v8s;   // 8 bf16 (4 VGPRs)
typedef __attribute__((ext_vector_type(4))) float  v4f;   // MFMA acc

#define MFMA_(a,b,c) __builtin_amdgcn_mfma_f32_16x16x32_bf16(a, b, c, 0, 0, 0)

__device__ __forceinline__ float sigmoidf_(float x) {
    return 1.0f / (1.0f + __expf(-x));
}
__device__ __forceinline__ unsigned short f2bf_rn(float f) {
    unsigned u = __float_as_uint(f);
    unsigned r = u + 0x7fffu + ((u >> 16) & 1u);
    return (unsigned short)(r >> 16);
}
__device__ __forceinline__ float bf2f(unsigned short h) {
    return __uint_as_float(((unsigned)h) << 16);
}

// One asm load, SHARED base register pair + immediate offset (round-7 post-mortem:
// per-load address pairs + 64 live frags = 256+ VGPRs -> scratch spills that
// re-serialized everything. This round caps live fragments at 32.)
#define ISSUE_OFF(dst, base, OFFB) \
    asm volatile("global_load_dwordx4 %0, %1, off offset:" #OFFB \
                 : "=v"(dst) : "v"(base) : "memory")

#define I16(f, b) do { \
    ISSUE_OFF(f[0],  b, 0);    ISSUE_OFF(f[1],  b, 64); \
    ISSUE_OFF(f[2],  b, 128);  ISSUE_OFF(f[3],  b, 192); \
    ISSUE_OFF(f[4],  b, 256);  ISSUE_OFF(f[5],  b, 320); \
    ISSUE_OFF(f[6],  b, 384);  ISSUE_OFF(f[7],  b, 448); \
    ISSUE_OFF(f[8],  b, 512);  ISSUE_OFF(f[9],  b, 576); \
    ISSUE_OFF(f[10], b, 640);  ISSUE_OFF(f[11], b, 704); \
    ISSUE_OFF(f[12], b, 768);  ISSUE_OFF(f[13], b, 832); \
    ISSUE_OFF(f[14], b, 896);  ISSUE_OFF(f[15], b, 960); \
} while (0)

#define WAITCNT_VM0 do { \
    asm volatile("s_waitcnt vmcnt(0)" ::: "memory"); \
    __builtin_amdgcn_sched_barrier(0); \
} while (0)

__global__ void __launch_bounds__(NTHR, 1)
deeplog_kernel(const int* __restrict__ x,
               const float* __restrict__ Wx1, const float* __restrict__ Wh1, const float* __restrict__ b1,
               const float* __restrict__ Wx2, const float* __restrict__ Wh2, const float* __restrict__ b2,
               const float* __restrict__ Wd,  const float* __restrict__ bd,
               float* __restrict__ out, void* __restrict__ wsv)
{
    extern __shared__ char smem[];
    unsigned short* wlds = (unsigned short*)smem;            // 6 x [16][520] bf16 weight regions
    float* zlds = (float*)(smem + ZOFF);                     // [2][64][20] f32 preactivations

    char* wsb = (char*)wsv;
    unsigned* flags = (unsigned*)(wsb + FLAG_OFF);           // flag[i] at flags[i*FLAG_STRIDE]
    unsigned short* Hbase = (unsigned short*)(wsb + H_OFF);
    unsigned short* H1hi[2] = { Hbase,           Hbase + 65536 };
    unsigned short* H1lo[2] = { Hbase + 131072,  Hbase + 196608 };
    unsigned short* H2hi[2] = { Hbase + 262144,  Hbase + 327680 };
    unsigned short* H2lo[2] = { Hbase + 393216,  Hbase + 458752 };
    // u32 views for pair-packed write-through stores (same memory, same layout)
    unsigned* H1hi32[2] = { (unsigned*)H1hi[0], (unsigned*)H1hi[1] };
    unsigned* H1lo32[2] = { (unsigned*)H1lo[0], (unsigned*)H1lo[1] };
    unsigned* H2hi32[2] = { (unsigned*)H2hi[0], (unsigned*)H2hi[1] };
    unsigned* H2lo32[2] = { (unsigned*)H2lo[0], (unsigned*)H2lo[1] };

    const int bid  = blockIdx.x;
    const int tid  = threadIdx.x;
    const int rb   = bid >> 7;           // 0..1 row-group
    const int cb   = bid & 127;          // 0..127 col-group
    const int b0   = rb * 64;            // first batch row of block
    const int n0   = cb * 4;             // first hidden unit of block
    const int fbase = rb << 7;           // flag base of my barrier group (0 or 128)

    const int lane = tid & 63;
    const int wv   = tid >> 6;           // wave 0..7
    const int isL2 = (wv >= 4);          // waves 4-7 -> layer 2
    const int wt   = isL2 ? (wv - 4) : wv;       // row-tile within block (16 rows each)
    const int kgrp = (lane >> 4) * 8;            // k-slot group for A/B fragments
    const int colb = (lane & 15) * WSTRIDE + kgrp;
    const int aoff = ((b0 + wt * 16 + (lane & 15)) << 9) + kgrp;  // row*512 + kgrp

    // gate-stage ownership: thread t -> layer (t>>8), cell (row=(t&255)>>2, nl=t&3)
    const int Lme  = tid >> 8;           // == isL2
    const int u    = tid & 255;
    const int grow = u >> 2;             // 0..63 local row
    const int nl   = u & 3;
    const int rowg = b0 + grow;          // global batch row
    const int n    = n0 + nl;            // global hidden unit

    // ---- one-time: stage split-bf16 weights to LDS (col-major, padded) ----
    for (int m = 0; m < 3; ++m) {
        const float* Wsrc = (m == 0) ? Wh1 : (m == 1) ? Wx2 : Wh2;
        unsigned short* dhi = wlds + (2 * m) * WREG;
        unsigned short* dlo = wlds + (2 * m + 1) * WREG;
        for (int i = tid; i < 8192; i += NTHR) {
            int k = i >> 4, c = i & 15;
            float v = Wsrc[(size_t)k * G4 + ((c >> 2) << 9) + n0 + (c & 3)];
            unsigned short hi = f2bf_rn(v);
            unsigned short lo = f2bf_rn(v - bf2f(hi));
            dhi[c * WSTRIDE + k] = hi;
            dlo[c * WSTRIDE + k] = lo;
        }
    }
    __syncthreads();

    const unsigned short* wh1h = wlds;
    const unsigned short* wh1l = wlds + WREG;
    const unsigned short* wx2h = wlds + 2 * WREG;
    const unsigned short* wx2l = wlds + 3 * WREG;
    const unsigned short* wh2h = wlds + 4 * WREG;
    const unsigned short* wh2l = wlds + 5 * WREG;

    // hoisted biases for owned cell (gate order i,f,g,o)
    const float* bsrc = Lme ? b2 : b1;
    float bias0 = bsrc[n], bias1 = bsrc[HH + n], bias2 = bsrc[2 * HH + n], bias3 = bsrc[3 * HH + n];

    float c_state = 0.0f;
    unsigned tgt = 1;

    #pragma unroll 1
    for (int p = 0; p <= TT; ++p) {
        // prefetch one-hot row of Wx1 for the gate stage (L1 waves only; their
        // vmcnt(0) waits are conservative over these parallel loads)
        float wx0 = 0.f, wx1v = 0.f, wx2v = 0.f, wx3v = 0.f;
        if (Lme == 0 && p < TT) {
            int xr = x[rowg * TT + p];
            const float* wxp = Wx1 + (size_t)xr * G4 + n;
            wx0 = wxp[0]; wx1v = wxp[HH]; wx2v = wxp[2 * HH]; wx3v = wxp[3 * HH];
        }

        // ---- MFMA GEMMs: 32-frag clusters (the register-file ceiling), g2 loads
        // interleaved under g1's MFMAs so their latency hides under compute ----
        const int q1 = (p - 1) & 1;   // parity holding h1(p-1)
        const int q2 = p & 1;         // parity holding h2(p-2)
        if (!isL2) {
            if (p < TT) {
                v4f accP = {0.f, 0.f, 0.f, 0.f}, accQ = {0.f, 0.f, 0.f, 0.f};
                v8s ah[16], al[16];
                const unsigned short* p1h = H1hi[q1] + aoff;
                const unsigned short* p1l = H1lo[q1] + aoff;
                I16(ah, p1h);
                I16(al, p1l);
                WAITCNT_VM0;
                const unsigned short* B1h = wh1h + colb;
                const unsigned short* B1l = wh1l + colb;
                #pragma unroll
                for (int kk = 0; kk < 16; ++kk) {
                    v8s bh = *(const v8s*)(B1h + kk * 32);
                    v8s bl = *(const v8s*)(B1l + kk * 32);
                    accP = MFMA_(ah[kk], bh, accP);
                    accQ = MFMA_(ah[kk], bl, accQ);
                    accP = MFMA_(al[kk], bl, accP);
                    accQ = MFMA_(al[kk], bh, accQ);
                }
                int r0 = wt * 16 + ((lane >> 4) << 2);
                #pragma unroll
                for (int q = 0; q < 4; ++q)
                    zlds[(r0 + q) * ZSTRIDE + (lane & 15)] = accP[q] + accQ[q];
            }
        } else {
            if (p >= 1) {
                v4f accP = {0.f, 0.f, 0.f, 0.f}, accQ = {0.f, 0.f, 0.f, 0.f};
                v8s a1h[16], a1l[16], a2h[16], a2l[16];
                const unsigned short* p1h = H1hi[q1] + aoff;
                const unsigned short* p1l = H1lo[q1] + aoff;
                const unsigned short* p2h = H2hi[q2] + aoff;
                const unsigned short* p2l = H2lo[q2] + aoff;
                I16(a1h, p1h);
                I16(a1l, p1l);
                WAITCNT_VM0;
                const unsigned short* B1h = wx2h + colb;
                const unsigned short* B1l = wx2l + colb;
                // g1 MFMAs with g2 loads drip-issued (liveness: a1[kk..] dies as a2[..kk] ramps)
                #define G1STEP(k, OFF) do { \
                    v8s bh = *(const v8s*)(B1h + (k) * 32); \
                    v8s bl = *(const v8s*)(B1l + (k) * 32); \
                    accP = MFMA_(a1h[k], bh, accP); \
                    accQ = MFMA_(a1h[k], bl, accQ); \
                    accP = MFMA_(a1l[k], bl, accP); \
                    accQ = MFMA_(a1l[k], bh, accQ); \
                    ISSUE_OFF(a2h[k], p2h, OFF); \
                    ISSUE_OFF(a2l[k], p2l, OFF); \
                } while (0)
                G1STEP(0, 0);    G1STEP(1, 64);   G1STEP(2, 128);  G1STEP(3, 192);
                G1STEP(4, 256);  G1STEP(5, 320);  G1STEP(6, 384);  G1STEP(7, 448);
                G1STEP(8, 512);  G1STEP(9, 576);  G1STEP(10, 640); G1STEP(11, 704);
                G1STEP(12, 768); G1STEP(13, 832); G1STEP(14, 896); G1STEP(15, 960);
                #undef G1STEP
                WAITCNT_VM0;
                const unsigned short* B2h = wh2h + colb;
                const unsigned short* B2l = wh2l + colb;
                #pragma unroll
                for (int kk = 0; kk < 16; ++kk) {
                    v8s bh = *(const v8s*)(B2h + kk * 32);
                    v8s bl = *(const v8s*)(B2l + kk * 32);
                    accP = MFMA_(a2h[kk], bh, accP);
                    accQ = MFMA_(a2h[kk], bl, accQ);
                    accP = MFMA_(a2l[kk], bl, accP);
                    accQ = MFMA_(a2l[kk], bh, accQ);
                }
                int r0 = wt * 16 + ((lane >> 4) << 2);
                #pragma unroll
                for (int q = 0; q < 4; ++q)
                    zlds[64 * ZSTRIDE + (r0 + q) * ZSTRIDE + (lane & 15)] = accP[q] + accQ[q];
            }
        }
        __syncthreads();

        // ---- gates: thread owns one (layer, row, n) cell; c-state in register.
        // h published as WRITE-THROUGH agent atomics (u32 = two adjacent n) so the
        // XCD L2 never holds dirty recurrent data -> no wbl2 needed at release. ----
        bool act = (Lme == 0) ? (p < TT) : (p >= 1);
        if (act) {
            const float* zrow = zlds + Lme * (64 * ZSTRIDE) + grow * ZSTRIDE;
            float z0 = zrow[nl]      + bias0;
            float z1 = zrow[4 + nl]  + bias1;
            float z2 = zrow[8 + nl]  + bias2;
            float z3 = zrow[12 + nl] + bias3;
            if (Lme == 0) { z0 += wx0; z1 += wx1v; z2 += wx2v; z3 += wx3v; }
            float gi = sigmoidf_(z0);
            float gf = sigmoidf_(z1);
            float gg = tanhf(z2);
            float go = sigmoidf_(z3);
            c_state  = gf * c_state + gi * gg;
            float h  = go * tanhf(c_state);
            unsigned hhi = f2bf_rn(h);
            unsigned hlo = f2bf_rn(h - bf2f((unsigned short)hhi));
            // pair with neighbor n^1 (adjacent lane, same wave; act is wave-uniform)
            unsigned ph = (unsigned)__shfl_xor((int)hhi, 1, 64);
            unsigned pl = (unsigned)__shfl_xor((int)hlo, 1, 64);
            if ((nl & 1) == 0) {
                unsigned hw = (hhi & 0xffffu) | (ph << 16);   // low half = even n
                unsigned lw = (hlo & 0xffffu) | (pl << 16);
                unsigned *dsthi, *dstlo;
                if (Lme == 0) { dsthi = H1hi32[p & 1];       dstlo = H1lo32[p & 1]; }
                else          { dsthi = H2hi32[(p - 1) & 1]; dstlo = H2lo32[(p - 1) & 1]; }
                int idx = rowg * 256 + (n >> 1);
                __hip_atomic_store(dsthi + idx, hw, __ATOMIC_RELAXED, __HIP_MEMORY_SCOPE_AGENT);
                __hip_atomic_store(dstlo + idx, lw, __ATOMIC_RELAXED, __HIP_MEMORY_SCOPE_AGENT);
            }
        }

        // ---- flag-array grid barrier, split by row-group; NO wbl2 anywhere ----
        __syncthreads();
        if (tid == 0) {
            asm volatile("s_waitcnt vmcnt(0)" ::: "memory");
            __hip_atomic_store(&flags[bid * FLAG_STRIDE], tgt,
                               __ATOMIC_RELAXED, __HIP_MEMORY_SCOPE_AGENT);
        }
        {
            const int nf = (p == TT) ? NBLK : 128;
            const int f0 = (p == TT) ? 0    : fbase;
            if (tid < nf) {
                while (__hip_atomic_load(&flags[(f0 + tid) * FLAG_STRIDE],
                                         __ATOMIC_RELAXED, __HIP_MEMORY_SCOPE_AGENT) < tgt)
                    __builtin_amdgcn_s_sleep(1);
            }
        }
        __syncthreads();
        // one acquire per block: invalidate L1/L2 so next phase's cached h reads refetch
        if (tid == 0)
            (void)__hip_atomic_load(&flags[bid * FLAG_STRIDE],
                                    __ATOMIC_ACQUIRE, __HIP_MEMORY_SCOPE_AGENT);
        ++tgt;
        __syncthreads();
    }

    // ---- final dense + softmax: block b handles output row b ----
    if (bid < BB) {
        const unsigned short* h2hi = H2hi[(TT - 1) & 1] + (size_t)bid * HH;
        const unsigned short* h2lo = H2lo[(TT - 1) & 1] + (size_t)bid * HH;
        float* hrow = zlds;            // 512 floats
        float* red  = zlds + HH;       // 512 floats
        hrow[tid] = bf2f(h2hi[tid]) + bf2f(h2lo[tid]);
        __syncthreads();

        float a0 = bd[tid], a1 = bd[tid + 512];
        const float* w = Wd + tid;
        #pragma unroll 4
        for (int k = 0; k < HH; ++k) {
            float hv = hrow[k];
            a0 += hv * w[(size_t)k * OUTN];
            a1 += hv * w[(size_t)k * OUTN + 512];
        }

        red[tid] = fmaxf(a0, a1);
        __syncthreads();
        for (int s = NTHR / 2; s > 0; s >>= 1) {
            if (tid < s) red[tid] = fmaxf(red[tid], red[tid + s]);
            __syncthreads();
        }
        float M = red[0];
        __syncthreads();
        float e0 = __expf(a0 - M), e1 = __expf(a1 - M);
        red[tid] = e0 + e1;
        __syncthreads();
        for (int s = NTHR / 2; s > 0; s >>= 1) {
            if (tid < s) red[tid] += red[tid + s];
            __syncthreads();
        }
        float inv = 1.0f / red[0];
        out[(size_t)bid * OUTN + tid]       = e0 * inv;
        out[(size_t)bid * OUTN + tid + 512] = e1 * inv;
    }
}

extern "C" void kernel_launch(void* const* d_in, const int* in_sizes, int n_in,
                              void* d_out, int out_size, void* d_ws, size_t ws_size,
                              hipStream_t stream) {
    (void)in_sizes; (void)n_in; (void)out_size; (void)ws_size;

    const int*   x   = (const int*)  d_in[0];
    const float* Wx1 = (const float*)d_in[1];
    const float* Wh1 = (const float*)d_in[2];
    const float* b1  = (const float*)d_in[3];
    const float* Wx2 = (const float*)d_in[4];
    const float* Wh2 = (const float*)d_in[5];
    const float* b2  = (const float*)d_in[6];
    const float* Wd  = (const float*)d_in[7];
    const float* bd  = (const float*)d_in[8];
    float* out = (float*)d_out;
    void* ws   = d_ws;

    (void)hipFuncSetAttribute((const void*)deeplog_kernel,
                              hipFuncAttributeMaxDynamicSharedMemorySize, LDS_BYTES);

    // zero: flags region (poisoned 0xAA would instantly satisfy >= tgt!) + h buffers
    size_t zero_bytes = H_OFF + (size_t)8 * BB * HH * sizeof(unsigned short);  // 1,081,344
    hipMemsetAsync(d_ws, 0, zero_bytes, stream);

    void* args[] = { &x, &Wx1, &Wh1, &b1, &Wx2, &Wh2, &b2, &Wd, &bd, &out, &ws };
    hipLaunchCooperativeKernel((const void*)deeplog_kernel,
                               dim3(NBLK), dim3(NTHR), args, LDS_BYTES, stream);
}